// Round 2
// baseline (454.167 us; speedup 1.0000x reference)
//
#include <hip/hip_runtime.h>
#include <hip/hip_bf16.h>
#include <math.h>
#include <stdint.h>

#define NT 256
constexpr int Hc = 1024, BOTc = 128, RDc = 48, Nc = 4096;
constexpr int ROWS = 8192;          // B*S
constexpr float INV_SQRT_RD = 0.14433756729740643f;  // 1/sqrt(48)

// ---------- small helpers ----------
__device__ __forceinline__ uint32_t umin32(uint32_t a, uint32_t b) { return a < b ? a : b; }
__device__ __forceinline__ uint32_t umax32(uint32_t a, uint32_t b) { return a > b ? a : b; }
__device__ __forceinline__ void ce_asc(uint32_t& x, uint32_t& y) {
  uint32_t lo = umin32(x, y), hi = umax32(x, y); x = lo; y = hi;
}
// pack: order-preserving float bits, low 12 bits replaced by slot idx (N=4096)
__device__ __forceinline__ uint32_t pack_score(float s, int slot) {
  uint32_t u = __float_as_uint(s);
  u = (u & 0x80000000u) ? ~u : (u | 0x80000000u);
  return (u & 0xFFFFF000u) | (uint32_t)slot;
}
__device__ __forceinline__ float unpack_score(uint32_t p) {
  uint32_t m = p & 0xFFFFF000u;
  uint32_t f = (m & 0x80000000u) ? (m ^ 0x80000000u) : ~m;
  return __uint_as_float(f);
}
// top-8 of two ascending 8-lists -> ascending, into a[]
__device__ __forceinline__ void merge_top8(uint32_t a[8], const uint32_t b[8]) {
  uint32_t m[8];
#pragma unroll
  for (int i = 0; i < 8; ++i) m[i] = umax32(a[i], b[7 - i]);   // bitonic, holds top-8
  ce_asc(m[0], m[4]); ce_asc(m[1], m[5]); ce_asc(m[2], m[6]); ce_asc(m[3], m[7]);
  ce_asc(m[0], m[2]); ce_asc(m[1], m[3]); ce_asc(m[4], m[6]); ce_asc(m[5], m[7]);
  ce_asc(m[0], m[1]); ce_asc(m[2], m[3]); ce_asc(m[4], m[5]); ce_asc(m[6], m[7]);
#pragma unroll
  for (int i = 0; i < 8; ++i) a[i] = m[i];
}

// ---------- W48 = router_w @ q_proj_w  [48,1024] ----------
__global__ void k_w48(const float* __restrict__ router_w, const float* __restrict__ q_proj_w,
                      float* __restrict__ W48) {
  __shared__ float rw[BOTc];
  int j = blockIdx.x;
  for (int d = threadIdx.x; d < BOTc; d += NT) rw[d] = router_w[j * BOTc + d];
  __syncthreads();
  for (int h = threadIdx.x; h < Hc; h += NT) {
    float acc = 0.f;
#pragma unroll 8
    for (int d = 0; d < BOTc; ++d) acc = fmaf(rw[d], q_proj_w[d * Hc + h], acc);
    W48[j * Hc + h] = acc;
  }
}

// ---------- rk_s[n,r] = (aux_keys[n] . router_w[r]) / sqrt(48) ----------
__global__ void k_rk(const float* __restrict__ aux_keys, const float* __restrict__ router_w,
                     float* __restrict__ rk_s) {
  int gid = blockIdx.x * NT + threadIdx.x;           // 4096*48 = 196608 exact
  int n = gid / RDc, r = gid - n * RDc;
  float acc = 0.f;
#pragma unroll 8
  for (int d = 0; d < BOTc; ++d) acc = fmaf(aux_keys[n * BOTc + d], router_w[r * BOTc + d], acc);
  rk_s[gid] = acc * INV_SQRT_RD;
}

// ---------- per-row variance -> log1p ----------
__global__ void k_var(const float* __restrict__ hidden, float* __restrict__ log_var) {
  int row = blockIdx.x;
  float4 v = reinterpret_cast<const float4*>(hidden + (size_t)row * Hc)[threadIdx.x];
  float s = v.x + v.y + v.z + v.w;
  float q = v.x * v.x + v.y * v.y + v.z * v.z + v.w * v.w;
#pragma unroll
  for (int d = 32; d >= 1; d >>= 1) { s += __shfl_down(s, d); q += __shfl_down(q, d); }
  __shared__ float ls[4], lq[4];
  int lane = threadIdx.x & 63, wid = threadIdx.x >> 6;
  if (lane == 0) { ls[wid] = s; lq[wid] = q; }
  __syncthreads();
  if (threadIdx.x == 0) {
    s = ls[0] + ls[1] + ls[2] + ls[3];
    q = lq[0] + lq[1] + lq[2] + lq[3];
    float mean = s * (1.f / Hc);
    float var = q * (1.f / Hc) - mean * mean;
    log_var[row] = log1pf(var);
  }
}

// ---------- global mean of log_var -> 1/(mean+1e-6) ----------
__global__ void k_redsum(const float* __restrict__ log_var, float* __restrict__ stats) {
  float s = 0.f;
  for (int i = threadIdx.x; i < ROWS; i += NT) s += log_var[i];
#pragma unroll
  for (int d = 32; d >= 1; d >>= 1) s += __shfl_down(s, d);
  __shared__ float ls[4];
  int lane = threadIdx.x & 63, wid = threadIdx.x >> 6;
  if (lane == 0) ls[wid] = s;
  __syncthreads();
  if (threadIdx.x == 0) {
    s = ls[0] + ls[1] + ls[2] + ls[3];
    stats[0] = 1.f / (s * (1.f / ROWS) + 1e-6f);
  }
}

// ---------- rq[8192,48] = hidden @ W48^T ----------
__global__ __launch_bounds__(256) void k_rq(const float* __restrict__ hidden,
                                            const float* __restrict__ W48,
                                            float* __restrict__ rq) {
  __shared__ float xs[32][33];
  __shared__ float wt[48][33];
  int row0 = blockIdx.x * 32;
  int tid = threadIdx.x;
  int cg = tid & 15, rg = tid >> 4;                  // rows rg*2..+1, cols cg+16j
  float acc[2][3] = {};
  for (int kk = 0; kk < Hc; kk += 32) {
    for (int t = tid; t < 32 * 32; t += NT) { int r = t >> 5, c = t & 31; xs[r][c] = hidden[(size_t)(row0 + r) * Hc + kk + c]; }
    for (int t = tid; t < 48 * 32; t += NT) { int r = t >> 5, c = t & 31; wt[r][c] = W48[r * Hc + kk + c]; }
    __syncthreads();
#pragma unroll 8
    for (int k = 0; k < 32; ++k) {
      float a0 = xs[rg * 2][k], a1 = xs[rg * 2 + 1][k];
#pragma unroll
      for (int j = 0; j < 3; ++j) {
        float b = wt[cg + 16 * j][k];
        acc[0][j] = fmaf(a0, b, acc[0][j]);
        acc[1][j] = fmaf(a1, b, acc[1][j]);
      }
    }
    __syncthreads();
  }
#pragma unroll
  for (int i = 0; i < 2; ++i)
#pragma unroll
    for (int j = 0; j < 3; ++j)
      rq[(size_t)(row0 + rg * 2 + i) * RDc + cg + 16 * j] = acc[i][j];
}

// ---------- uncertainty MLP partials: learned2[row][2] ----------
__global__ __launch_bounds__(256) void k_unc(const float* __restrict__ hidden,
                                             const float* __restrict__ w1,
                                             const float* __restrict__ b1,
                                             const float* __restrict__ w2,
                                             float* __restrict__ learned2) {
  __shared__ float xs[32][33];
  __shared__ float ws1[128][33];
  __shared__ float red[32][33];
  int rowg = blockIdx.x >> 1, ch = blockIdx.x & 1;
  int row0 = rowg * 32, col0 = ch * 128;
  int tid = threadIdx.x;
  int cg = tid & 31, rg = tid >> 5;                  // rows rg*4..+3, cols cg+32j (j<4)
  float acc[4][4] = {};
  for (int kk = 0; kk < Hc; kk += 32) {
    for (int t = tid; t < 32 * 32; t += NT) { int r = t >> 5, c = t & 31; xs[r][c] = hidden[(size_t)(row0 + r) * Hc + kk + c]; }
    for (int t = tid; t < 128 * 32; t += NT) { int r = t >> 5, c = t & 31; ws1[r][c] = w1[(size_t)(col0 + r) * Hc + kk + c]; }
    __syncthreads();
#pragma unroll 8
    for (int k = 0; k < 32; ++k) {
      float a[4], b[4];
#pragma unroll
      for (int i = 0; i < 4; ++i) a[i] = xs[rg * 4 + i][k];
#pragma unroll
      for (int j = 0; j < 4; ++j) b[j] = ws1[cg + 32 * j][k];
#pragma unroll
      for (int i = 0; i < 4; ++i)
#pragma unroll
        for (int j = 0; j < 4; ++j) acc[i][j] = fmaf(a[i], b[j], acc[i][j]);
    }
    __syncthreads();
  }
  float part[4];
#pragma unroll
  for (int i = 0; i < 4; ++i) {
    part[i] = 0.f;
#pragma unroll
    for (int j = 0; j < 4; ++j) {
      int col = col0 + cg + 32 * j;
      float x = acc[i][j] + b1[col];
      float g = 0.5f * x * (1.f + erff(x * 0.70710678118654752f));   // exact gelu
      part[i] = fmaf(g, w2[col], part[i]);
    }
  }
#pragma unroll
  for (int i = 0; i < 4; ++i) red[rg * 4 + i][cg] = part[i];
  __syncthreads();
  if (tid < 32) {
    float s = 0.f;
#pragma unroll 8
    for (int c = 0; c < 32; ++c) s += red[tid][c];
    learned2[(size_t)(row0 + tid) * 2 + ch] = s;
  }
}

// ---------- fused scores + per-range top-8 ----------
// grid: (8192/32 rowgroups) x 4 slot-ranges; block 256
__global__ __launch_bounds__(256) void k_scores(const float* __restrict__ rq,
                                                const float* __restrict__ rk_s,
                                                const float* __restrict__ rel,
                                                uint32_t* __restrict__ cand) {
  __shared__ float rqs[32][49];
  __shared__ float rks[128][49];
  __shared__ float rel_s[128];
  int rowg = blockIdx.x >> 2, range = blockIdx.x & 3;
  int row0 = rowg * 32;
  int sbase = range * 1024;
  int tid = threadIdx.x;
  int sg = tid & 31, rg = tid >> 5;                  // rows rg*4..+3 ; slots sg+32j
  for (int t = tid; t < 32 * RDc; t += NT) { int r = t / RDc, c = t - r * RDc; rqs[r][c] = rq[(size_t)(row0 + r) * RDc + c]; }
  uint32_t top[4][8];
#pragma unroll
  for (int i = 0; i < 4; ++i)
#pragma unroll
    for (int q = 0; q < 8; ++q) top[i][q] = 0u;

  for (int tile = 0; tile < 8; ++tile) {
    int s0 = sbase + tile * 128;
    for (int t = tid; t < 128 * RDc; t += NT) { int r = t / RDc, c = t - r * RDc; rks[r][c] = rk_s[(size_t)(s0 + r) * RDc + c]; }
    if (tid < 128) rel_s[tid] = rel[s0 + tid];
    __syncthreads();

    float acc[4][4] = {};
#pragma unroll 4
    for (int k = 0; k < RDc; ++k) {
      float a0 = rqs[rg * 4 + 0][k], a1 = rqs[rg * 4 + 1][k];
      float a2 = rqs[rg * 4 + 2][k], a3 = rqs[rg * 4 + 3][k];
#pragma unroll
      for (int j = 0; j < 4; ++j) {
        float b = rks[sg + 32 * j][k];
        acc[0][j] = fmaf(a0, b, acc[0][j]);
        acc[1][j] = fmaf(a1, b, acc[1][j]);
        acc[2][j] = fmaf(a2, b, acc[2][j]);
        acc[3][j] = fmaf(a3, b, acc[3][j]);
      }
    }
#pragma unroll
    for (int j = 0; j < 4; ++j) {
      int sl = sg + 32 * j;
      int slot = s0 + sl;
      float rl = rel_s[sl];
#pragma unroll
      for (int i = 0; i < 4; ++i) {
        uint32_t p = pack_score(acc[i][j] + rl, slot);
        if (p > top[i][0]) {                        // > current min -> insert
          top[i][0] = p;
          ce_asc(top[i][0], top[i][1]); ce_asc(top[i][1], top[i][2]);
          ce_asc(top[i][2], top[i][3]); ce_asc(top[i][3], top[i][4]);
          ce_asc(top[i][4], top[i][5]); ce_asc(top[i][5], top[i][6]);
          ce_asc(top[i][6], top[i][7]);
        }
      }
    }
    __syncthreads();
  }
  // half-wave butterfly merge over sg (32 lanes share each row)
#pragma unroll
  for (int i = 0; i < 4; ++i) {
#pragma unroll
    for (int dd = 0; dd < 5; ++dd) {
      int d = 1 << dd;
      uint32_t o[8];
#pragma unroll
      for (int q = 0; q < 8; ++q) o[q] = __shfl_xor(top[i][q], d);
      merge_top8(top[i], o);
    }
  }
  if (sg == 0) {
#pragma unroll
    for (int i = 0; i < 4; ++i) {
      int row = row0 + rg * 4 + i;
#pragma unroll
      for (int q = 0; q < 8; ++q) cand[((size_t)row * 4 + range) * 8 + q] = top[i][q];
    }
  }
}

// ---------- merge 4 range-lists, softmax ----------
__global__ void k_topk(const uint32_t* __restrict__ cand, float* __restrict__ topw,
                       int* __restrict__ topidx) {
  int row = blockIdx.x * NT + threadIdx.x;
  uint32_t l0[8], l1[8], l2[8], l3[8];
  const uint32_t* c = cand + (size_t)row * 32;
#pragma unroll
  for (int q = 0; q < 8; ++q) { l0[q] = c[q]; l1[q] = c[8 + q]; l2[q] = c[16 + q]; l3[q] = c[24 + q]; }
  merge_top8(l0, l1);
  merge_top8(l2, l3);
  merge_top8(l0, l2);                                // l0 = global top-8 (asc)
  float sc[8];
#pragma unroll
  for (int q = 0; q < 8; ++q) sc[q] = unpack_score(l0[q]);
  float mx = sc[7];
  float e[8]; float sum = 0.f;
#pragma unroll
  for (int q = 0; q < 8; ++q) { e[q] = expf(sc[q] - mx); sum += e[q]; }
  float inv = 1.f / sum;
#pragma unroll
  for (int q = 0; q < 8; ++q) {
    topw[(size_t)row * 8 + q] = e[7 - q] * inv;
    topidx[(size_t)row * 8 + q] = (int)(l0[7 - q] & 0xFFFu);
  }
}

// ---------- gather + gate + output (fp32) ----------
__global__ __launch_bounds__(256) void k_final(const float* __restrict__ hidden,
                                               const float* __restrict__ aux_values,
                                               const float* __restrict__ topw,
                                               const int* __restrict__ topidx,
                                               const float* __restrict__ log_var,
                                               const float* __restrict__ learned2,
                                               const float* __restrict__ stats,
                                               const float* __restrict__ b2,
                                               const float* __restrict__ gw,
                                               const float* __restrict__ gb,
                                               float* __restrict__ out) {
  int row = blockIdx.x;
  int tid = threadIdx.x;
  __shared__ float ws_[8]; __shared__ int wi_[8]; __shared__ float sgate;
  if (tid < 8) { ws_[tid] = topw[(size_t)row * 8 + tid]; wi_[tid] = topidx[(size_t)row * 8 + tid]; }
  if (tid == 0) {
    float learned = learned2[row * 2] + learned2[row * 2 + 1] + b2[0];
    float nv = log_var[row] * stats[0];
    float sig = 1.f / (1.f + expf(-learned));
    float u = nv * 0.5f + sig * 2.5f;
    u = fminf(fmaxf(u, 0.f), 5.f);
    sgate = 1.f / (1.f + expf(-(gw[0] * u + gb[0])));
  }
  __syncthreads();
  int h0 = tid * 4;
  float4 hv = *reinterpret_cast<const float4*>(hidden + (size_t)row * Hc + h0);
  float ax = 0.f, ay = 0.f, az = 0.f, aw = 0.f;
#pragma unroll
  for (int k = 0; k < 8; ++k) {
    float w = ws_[k];
    float4 v = *reinterpret_cast<const float4*>(aux_values + (size_t)wi_[k] * Hc + h0);
    ax = fmaf(w, v.x, ax); ay = fmaf(w, v.y, ay); az = fmaf(w, v.z, az); aw = fmaf(w, v.w, aw);
  }
  float g = sgate;
  float4 o;
  o.x = hv.x + g * ax; o.y = hv.y + g * ay; o.z = hv.z + g * az; o.w = hv.w + g * aw;
  *reinterpret_cast<float4*>(out + (size_t)row * Hc + h0) = o;
}

extern "C" void kernel_launch(void* const* d_in, const int* in_sizes, int n_in,
                              void* d_out, int out_size, void* d_ws, size_t ws_size,
                              hipStream_t stream) {
  const float* hidden     = (const float*)d_in[0];
  const float* q_proj_w   = (const float*)d_in[1];
  const float* router_w   = (const float*)d_in[2];
  const float* aux_keys   = (const float*)d_in[3];
  const float* aux_values = (const float*)d_in[4];
  const float* rel        = (const float*)d_in[5];
  const float* unc_w1     = (const float*)d_in[6];
  const float* unc_b1     = (const float*)d_in[7];
  const float* unc_w2     = (const float*)d_in[8];
  const float* unc_b2     = (const float*)d_in[9];
  const float* gate_w1    = (const float*)d_in[10];
  const float* gate_bias  = (const float*)d_in[11];
  float* out = (float*)d_out;

  float* ws = (float*)d_ws;                 // ~4.3 MB used
  float* W48      = ws;                     // 48*1024        = 49152
  float* rk_s     = W48 + 49152;            // 4096*48        = 196608
  float* rq       = rk_s + 196608;          // 8192*48        = 393216
  float* log_var  = rq + 393216;            // 8192
  float* learned2 = log_var + 8192;         // 8192*2         = 16384
  float* stats    = learned2 + 16384;       // 8
  uint32_t* cand  = (uint32_t*)(stats + 8); // 8192*4*8       = 262144
  float* topw     = (float*)(cand + 262144);// 8192*8         = 65536
  int* topidx     = (int*)(topw + 65536);   // 8192*8         = 65536

  k_w48<<<48, NT, 0, stream>>>(router_w, q_proj_w, W48);
  k_rk<<<768, NT, 0, stream>>>(aux_keys, router_w, rk_s);
  k_var<<<8192, NT, 0, stream>>>(hidden, log_var);
  k_redsum<<<1, NT, 0, stream>>>(log_var, stats);
  k_rq<<<256, NT, 0, stream>>>(hidden, W48, rq);
  k_unc<<<512, NT, 0, stream>>>(hidden, unc_w1, unc_b1, unc_w2, learned2);
  k_scores<<<1024, NT, 0, stream>>>(rq, rk_s, rel, cand);
  k_topk<<<32, NT, 0, stream>>>(cand, topw, topidx);
  k_final<<<8192, NT, 0, stream>>>(hidden, aux_values, topw, topidx, log_var, learned2,
                                   stats, unc_b2, gate_w1, gate_bias, out);
}

// Round 3
// 200.651 us; speedup vs baseline: 2.2635x; 2.2635x over previous
//
#include <hip/hip_runtime.h>
#include <hip/hip_bf16.h>
#include <math.h>
#include <stdint.h>

#define NT 256
constexpr int Hc = 1024, BOTc = 128, RDc = 48, Nc = 4096;
constexpr int ROWS = 8192;          // B*S
constexpr float INV_SQRT_RD = 0.14433756729740643f;  // 1/sqrt(48)

typedef short bf16x8 __attribute__((ext_vector_type(8)));
typedef float f32x4 __attribute__((ext_vector_type(4)));

// ---------- small helpers ----------
__device__ __forceinline__ uint32_t umin32(uint32_t a, uint32_t b) { return a < b ? a : b; }
__device__ __forceinline__ uint32_t umax32(uint32_t a, uint32_t b) { return a > b ? a : b; }
__device__ __forceinline__ void ce_asc(uint32_t& x, uint32_t& y) {
  uint32_t lo = umin32(x, y), hi = umax32(x, y); x = lo; y = hi;
}
// pack: order-preserving float bits, low 12 bits replaced by slot idx (N=4096)
__device__ __forceinline__ uint32_t pack_score(float s, int slot) {
  uint32_t u = __float_as_uint(s);
  u = (u & 0x80000000u) ? ~u : (u | 0x80000000u);
  return (u & 0xFFFFF000u) | (uint32_t)slot;
}
__device__ __forceinline__ float unpack_score(uint32_t p) {
  uint32_t m = p & 0xFFFFF000u;
  uint32_t f = (m & 0x80000000u) ? (m ^ 0x80000000u) : ~m;
  return __uint_as_float(f);
}
// top-8 of two ascending 8-lists -> ascending, into a[]
__device__ __forceinline__ void merge_top8(uint32_t a[8], const uint32_t b[8]) {
  uint32_t m[8];
#pragma unroll
  for (int i = 0; i < 8; ++i) m[i] = umax32(a[i], b[7 - i]);   // bitonic, holds top-8
  ce_asc(m[0], m[4]); ce_asc(m[1], m[5]); ce_asc(m[2], m[6]); ce_asc(m[3], m[7]);
  ce_asc(m[0], m[2]); ce_asc(m[1], m[3]); ce_asc(m[4], m[6]); ce_asc(m[5], m[7]);
  ce_asc(m[0], m[1]); ce_asc(m[2], m[3]); ce_asc(m[4], m[5]); ce_asc(m[6], m[7]);
#pragma unroll
  for (int i = 0; i < 8; ++i) a[i] = m[i];
}
__device__ __forceinline__ uint16_t bf16bits(float x) {      // RNE
  uint32_t u = __float_as_uint(x);
  return (uint16_t)(((u + 0x7FFFu + ((u >> 16) & 1u)) >> 16) & 0xFFFFu);
}

// ---------- hidden -> bf16 (xb) + per-row variance ----------
__global__ void k_hb(const float* __restrict__ hidden, uint16_t* __restrict__ xb,
                     float* __restrict__ log_var) {
  int row = blockIdx.x;
  float4 v = reinterpret_cast<const float4*>(hidden + (size_t)row * Hc)[threadIdx.x];
  ushort4 h;
  h.x = bf16bits(v.x); h.y = bf16bits(v.y); h.z = bf16bits(v.z); h.w = bf16bits(v.w);
  *reinterpret_cast<ushort4*>(xb + (size_t)row * Hc + threadIdx.x * 4) = h;
  float s = v.x + v.y + v.z + v.w;
  float q = v.x * v.x + v.y * v.y + v.z * v.z + v.w * v.w;
#pragma unroll
  for (int d = 32; d >= 1; d >>= 1) { s += __shfl_down(s, d); q += __shfl_down(q, d); }
  __shared__ float ls[4], lq[4];
  int lane = threadIdx.x & 63, wid = threadIdx.x >> 6;
  if (lane == 0) { ls[wid] = s; lq[wid] = q; }
  __syncthreads();
  if (threadIdx.x == 0) {
    s = ls[0] + ls[1] + ls[2] + ls[3];
    q = lq[0] + lq[1] + lq[2] + lq[3];
    float mean = s * (1.f / Hc);
    float var = q * (1.f / Hc) - mean * mean;
    log_var[row] = log1pf(var);
  }
}

// ---------- global mean of log_var -> 1/(mean+1e-6) ----------
__global__ void k_redsum(const float* __restrict__ log_var, float* __restrict__ stats) {
  float s = 0.f;
  for (int i = threadIdx.x; i < ROWS; i += NT) s += log_var[i];
#pragma unroll
  for (int d = 32; d >= 1; d >>= 1) s += __shfl_down(s, d);
  __shared__ float ls[4];
  int lane = threadIdx.x & 63, wid = threadIdx.x >> 6;
  if (lane == 0) ls[wid] = s;
  __syncthreads();
  if (threadIdx.x == 0) {
    s = ls[0] + ls[1] + ls[2] + ls[3];
    stats[0] = 1.f / (s * (1.f / ROWS) + 1e-6f);
  }
}

// ---------- W48b = bf16(router_w @ q_proj_w)  [48,1024] ----------
__global__ void k_w48(const float* __restrict__ router_w, const float* __restrict__ q_proj_w,
                      uint16_t* __restrict__ W48b) {
  __shared__ float rw[BOTc];
  int j = blockIdx.x;
  for (int d = threadIdx.x; d < BOTc; d += NT) rw[d] = router_w[j * BOTc + d];
  __syncthreads();
  for (int h = threadIdx.x; h < Hc; h += NT) {
    float acc = 0.f;
#pragma unroll 8
    for (int d = 0; d < BOTc; ++d) acc = fmaf(rw[d], q_proj_w[d * Hc + h], acc);
    W48b[j * Hc + h] = bf16bits(acc);
  }
}

// ---------- w1 fp32 -> bf16 ----------
__global__ void k_cvt(const float* __restrict__ src, uint16_t* __restrict__ dst) {
  int i = blockIdx.x * NT + threadIdx.x;
  float4 v = reinterpret_cast<const float4*>(src)[i];
  ushort4 h;
  h.x = bf16bits(v.x); h.y = bf16bits(v.y); h.z = bf16bits(v.z); h.w = bf16bits(v.w);
  reinterpret_cast<ushort4*>(dst)[i] = h;
}

// ---------- rk_b[n][64]: cols 0-47 = (aux_keys[n].router_w[r])/sqrt48, col48 = rel, 49-63 = 0 ----------
__global__ void k_rk(const float* __restrict__ aux_keys, const float* __restrict__ router_w,
                     const float* __restrict__ rel, uint16_t* __restrict__ rk_b) {
  int gid = blockIdx.x * NT + threadIdx.x;           // 4096*48 = 196608 exact
  int n = gid / RDc, r = gid - n * RDc;
  float acc = 0.f;
#pragma unroll 8
  for (int d = 0; d < BOTc; ++d) acc = fmaf(aux_keys[n * BOTc + d], router_w[r * BOTc + d], acc);
  rk_b[(size_t)n * 64 + r] = bf16bits(acc * INV_SQRT_RD);
  if (r < 16) rk_b[(size_t)n * 64 + 48 + r] = (r == 0) ? bf16bits(rel[n]) : (uint16_t)0;
}

// ---------- rq_b[8192][64] = bf16(xb @ W48b^T), col48 = 1.0, 49-63 = 0 ----------
__global__ __launch_bounds__(256) void k_rq_mfma(const uint16_t* __restrict__ xb,
                                                 const uint16_t* __restrict__ W48b,
                                                 uint16_t* __restrict__ rq_b) {
  int tid = threadIdx.x, wave = tid >> 6, lane = tid & 63;
  int l15 = lane & 15, lg = lane >> 4;
  int row0 = blockIdx.x * 64 + wave * 16;
  f32x4 acc[3] = {};
  const uint16_t* xrow = xb + (size_t)(row0 + l15) * Hc + lg * 8;
  const uint16_t* wrow = W48b + (size_t)l15 * Hc + lg * 8;
  for (int kk = 0; kk < Hc; kk += 32) {
    bf16x8 a = *reinterpret_cast<const bf16x8*>(xrow + kk);
#pragma unroll
    for (int t = 0; t < 3; ++t) {
      bf16x8 b = *reinterpret_cast<const bf16x8*>(wrow + (size_t)t * 16 * Hc + kk);
      acc[t] = __builtin_amdgcn_mfma_f32_16x16x32_bf16(a, b, acc[t], 0, 0, 0);
    }
  }
#pragma unroll
  for (int t = 0; t < 3; ++t)
#pragma unroll
    for (int r = 0; r < 4; ++r) {
      int q = row0 + lg * 4 + r;
      rq_b[(size_t)q * 64 + t * 16 + l15] = bf16bits(acc[t][r]);
    }
  if (lane < 16) {
    int q = row0 + lane;
    uint32_t* p = reinterpret_cast<uint32_t*>(rq_b + (size_t)q * 64 + 48);
    p[0] = 0x00003F80u;  // bf16(1.0), 0
    p[1] = 0u; p[2] = 0u; p[3] = 0u;
    p[4] = 0u; p[5] = 0u; p[6] = 0u; p[7] = 0u;
  }
}

// ---------- uncertainty MLP via MFMA: learned2[row][2] ----------
__global__ __launch_bounds__(256) void k_unc_mfma(const uint16_t* __restrict__ xb,
                                                  const uint16_t* __restrict__ w1b,
                                                  const float* __restrict__ b1,
                                                  const float* __restrict__ w2,
                                                  float* __restrict__ learned2) {
  int tid = threadIdx.x, wave = tid >> 6, lane = tid & 63;
  int l15 = lane & 15, lg = lane >> 4;
  int rowg = blockIdx.x >> 1, ch = blockIdx.x & 1;
  int row0 = rowg * 64 + wave * 16;
  int n0 = ch * 128;
  float b1s[8], w2s[8];
#pragma unroll
  for (int t = 0; t < 8; ++t) { int n = n0 + t * 16 + l15; b1s[t] = b1[n]; w2s[t] = w2[n]; }
  f32x4 acc[8] = {};
  const uint16_t* xrow = xb + (size_t)(row0 + l15) * Hc + lg * 8;
  const uint16_t* wrow = w1b + (size_t)(n0 + l15) * Hc + lg * 8;
  for (int kk = 0; kk < Hc; kk += 32) {
    bf16x8 a = *reinterpret_cast<const bf16x8*>(xrow + kk);
#pragma unroll
    for (int t = 0; t < 8; ++t) {
      bf16x8 b = *reinterpret_cast<const bf16x8*>(wrow + (size_t)t * 16 * Hc + kk);
      acc[t] = __builtin_amdgcn_mfma_f32_16x16x32_bf16(a, b, acc[t], 0, 0, 0);
    }
  }
  float part[4] = {0.f, 0.f, 0.f, 0.f};
#pragma unroll
  for (int t = 0; t < 8; ++t)
#pragma unroll
    for (int r = 0; r < 4; ++r) {
      float x = acc[t][r] + b1s[t];
      float g = 0.5f * x * (1.f + erff(x * 0.70710678118654752f));
      part[r] = fmaf(g, w2s[t], part[r]);
    }
#pragma unroll
  for (int d = 1; d < 16; d <<= 1) {
#pragma unroll
    for (int r = 0; r < 4; ++r) part[r] += __shfl_xor(part[r], d);
  }
  if (l15 == 0) {
#pragma unroll
    for (int r = 0; r < 4; ++r)
      learned2[(size_t)(row0 + lg * 4 + r) * 2 + ch] = part[r];
  }
}

// ---------- scores via MFMA (swapped operands) + in-register top-8 ----------
// D = rk_tile[16 slots x K] . rq_tile[K x 16 q]: lane holds q = lane&15 (fixed),
// slots (lane>>4)*4 + r. rel folded in as K-column 48 (rq col48 = 1.0).
__global__ __launch_bounds__(256) void k_scores_mfma(const uint16_t* __restrict__ rq_b,
                                                     const uint16_t* __restrict__ rk_b,
                                                     uint32_t* __restrict__ cand) {
  int tid = threadIdx.x, wave = tid >> 6, lane = tid & 63;
  int l15 = lane & 15, lg = lane >> 4;
  int rowg = blockIdx.x >> 2, range = blockIdx.x & 3;
  int q0 = rowg * 64 + wave * 16;
  const uint16_t* qp = rq_b + (size_t)(q0 + l15) * 64 + lg * 8;
  bf16x8 b1 = *reinterpret_cast<const bf16x8*>(qp);
  bf16x8 b2 = *reinterpret_cast<const bf16x8*>(qp + 32);
  uint32_t top[8];
#pragma unroll
  for (int q = 0; q < 8; ++q) top[q] = 0u;
  int sbase = range * 1024;
  for (int t = 0; t < 64; ++t) {
    int s0 = sbase + t * 16;
    const uint16_t* kp = rk_b + (size_t)(s0 + l15) * 64 + lg * 8;
    bf16x8 a1 = *reinterpret_cast<const bf16x8*>(kp);
    bf16x8 a2 = *reinterpret_cast<const bf16x8*>(kp + 32);
    f32x4 acc = {0.f, 0.f, 0.f, 0.f};
    acc = __builtin_amdgcn_mfma_f32_16x16x32_bf16(a1, b1, acc, 0, 0, 0);
    acc = __builtin_amdgcn_mfma_f32_16x16x32_bf16(a2, b2, acc, 0, 0, 0);
#pragma unroll
    for (int r = 0; r < 4; ++r) {
      uint32_t p = pack_score(acc[r], s0 + lg * 4 + r);
      if (p > top[0]) {
        top[0] = p;
        ce_asc(top[0], top[1]); ce_asc(top[1], top[2]); ce_asc(top[2], top[3]);
        ce_asc(top[3], top[4]); ce_asc(top[4], top[5]); ce_asc(top[5], top[6]);
        ce_asc(top[6], top[7]);
      }
    }
  }
  // merge across the 4 lane-groups holding the same q (xor 16, 32)
#pragma unroll
  for (int dd = 16; dd <= 32; dd <<= 1) {
    uint32_t o[8];
#pragma unroll
    for (int q = 0; q < 8; ++q) o[q] = __shfl_xor(top[q], dd);
    merge_top8(top, o);
  }
  if (lg == 0) {
    int row = q0 + l15;
#pragma unroll
    for (int q = 0; q < 8; ++q) cand[((size_t)row * 4 + range) * 8 + q] = top[q];
  }
}

// ---------- merge 4 range-lists, softmax ----------
__global__ void k_topk(const uint32_t* __restrict__ cand, float* __restrict__ topw,
                       int* __restrict__ topidx) {
  int row = blockIdx.x * NT + threadIdx.x;
  uint32_t l0[8], l1[8], l2[8], l3[8];
  const uint32_t* c = cand + (size_t)row * 32;
#pragma unroll
  for (int q = 0; q < 8; ++q) { l0[q] = c[q]; l1[q] = c[8 + q]; l2[q] = c[16 + q]; l3[q] = c[24 + q]; }
  merge_top8(l0, l1);
  merge_top8(l2, l3);
  merge_top8(l0, l2);                                // l0 = global top-8 (asc)
  float sc[8];
#pragma unroll
  for (int q = 0; q < 8; ++q) sc[q] = unpack_score(l0[q]);
  float mx = sc[7];
  float e[8]; float sum = 0.f;
#pragma unroll
  for (int q = 0; q < 8; ++q) { e[q] = expf(sc[q] - mx); sum += e[q]; }
  float inv = 1.f / sum;
#pragma unroll
  for (int q = 0; q < 8; ++q) {
    topw[(size_t)row * 8 + q] = e[7 - q] * inv;
    topidx[(size_t)row * 8 + q] = (int)(l0[7 - q] & 0xFFFu);
  }
}

// ---------- gather + gate + output (fp32) ----------
__global__ __launch_bounds__(256) void k_final(const float* __restrict__ hidden,
                                               const float* __restrict__ aux_values,
                                               const float* __restrict__ topw,
                                               const int* __restrict__ topidx,
                                               const float* __restrict__ log_var,
                                               const float* __restrict__ learned2,
                                               const float* __restrict__ stats,
                                               const float* __restrict__ b2,
                                               const float* __restrict__ gw,
                                               const float* __restrict__ gb,
                                               float* __restrict__ out) {
  int row = blockIdx.x;
  int tid = threadIdx.x;
  __shared__ float ws_[8]; __shared__ int wi_[8]; __shared__ float sgate;
  if (tid < 8) { ws_[tid] = topw[(size_t)row * 8 + tid]; wi_[tid] = topidx[(size_t)row * 8 + tid]; }
  if (tid == 0) {
    float learned = learned2[row * 2] + learned2[row * 2 + 1] + b2[0];
    float nv = log_var[row] * stats[0];
    float sig = 1.f / (1.f + expf(-learned));
    float u = nv * 0.5f + sig * 2.5f;
    u = fminf(fmaxf(u, 0.f), 5.f);
    sgate = 1.f / (1.f + expf(-(gw[0] * u + gb[0])));
  }
  __syncthreads();
  int h0 = tid * 4;
  float4 hv = *reinterpret_cast<const float4*>(hidden + (size_t)row * Hc + h0);
  float ax = 0.f, ay = 0.f, az = 0.f, aw = 0.f;
#pragma unroll
  for (int k = 0; k < 8; ++k) {
    float w = ws_[k];
    float4 v = *reinterpret_cast<const float4*>(aux_values + (size_t)wi_[k] * Hc + h0);
    ax = fmaf(w, v.x, ax); ay = fmaf(w, v.y, ay); az = fmaf(w, v.z, az); aw = fmaf(w, v.w, aw);
  }
  float g = sgate;
  float4 o;
  o.x = hv.x + g * ax; o.y = hv.y + g * ay; o.z = hv.z + g * az; o.w = hv.w + g * aw;
  *reinterpret_cast<float4*>(out + (size_t)row * Hc + h0) = o;
}

extern "C" void kernel_launch(void* const* d_in, const int* in_sizes, int n_in,
                              void* d_out, int out_size, void* d_ws, size_t ws_size,
                              hipStream_t stream) {
  const float* hidden     = (const float*)d_in[0];
  const float* q_proj_w   = (const float*)d_in[1];
  const float* router_w   = (const float*)d_in[2];
  const float* aux_keys   = (const float*)d_in[3];
  const float* aux_values = (const float*)d_in[4];
  const float* rel        = (const float*)d_in[5];
  const float* unc_w1     = (const float*)d_in[6];
  const float* unc_b1     = (const float*)d_in[7];
  const float* unc_w2     = (const float*)d_in[8];
  const float* unc_b2     = (const float*)d_in[9];
  const float* gate_w1    = (const float*)d_in[10];
  const float* gate_bias  = (const float*)d_in[11];
  float* out = (float*)d_out;

  uint8_t* w = (uint8_t*)d_ws;              // ~20.6 MB used
  uint16_t* xb    = (uint16_t*)w;                 w += (size_t)ROWS * Hc * 2;     // 16 MB
  uint16_t* w1b   = (uint16_t*)w;                 w += (size_t)256 * Hc * 2;      // 512 KB
  uint16_t* W48b  = (uint16_t*)w;                 w += (size_t)48 * Hc * 2;       // 96 KB
  uint16_t* rq_b  = (uint16_t*)w;                 w += (size_t)ROWS * 64 * 2;     // 1 MB
  uint16_t* rk_b  = (uint16_t*)w;                 w += (size_t)Nc * 64 * 2;       // 512 KB
  float* log_var  = (float*)w;                    w += (size_t)ROWS * 4;
  float* learned2 = (float*)w;                    w += (size_t)ROWS * 2 * 4;
  float* stats    = (float*)w;                    w += 256;
  uint32_t* cand  = (uint32_t*)w;                 w += (size_t)ROWS * 32 * 4;     // 1 MB
  float* topw     = (float*)w;                    w += (size_t)ROWS * 8 * 4;
  int* topidx     = (int*)w;                      w += (size_t)ROWS * 8 * 4;

  k_w48<<<48, NT, 0, stream>>>(router_w, q_proj_w, W48b);
  k_cvt<<<256, NT, 0, stream>>>(unc_w1, w1b);               // 256*1024/4/256 = 256 blocks
  k_rk<<<768, NT, 0, stream>>>(aux_keys, router_w, rel, rk_b);
  k_hb<<<ROWS, NT, 0, stream>>>(hidden, xb, log_var);
  k_redsum<<<1, NT, 0, stream>>>(log_var, stats);
  k_rq_mfma<<<ROWS / 64, NT, 0, stream>>>(xb, W48b, rq_b);          // 128 blocks
  k_unc_mfma<<<(ROWS / 64) * 2, NT, 0, stream>>>(xb, w1b, unc_b1, unc_w2, learned2); // 256
  k_scores_mfma<<<(ROWS / 64) * 4, NT, 0, stream>>>(rq_b, rk_b, cand);               // 512
  k_topk<<<ROWS / NT, NT, 0, stream>>>(cand, topw, topidx);
  k_final<<<ROWS, NT, 0, stream>>>(hidden, aux_values, topw, topidx, log_var, learned2,
                                   stats, unc_b2, gate_w1, gate_bias, out);
}

// Round 4
// 192.541 us; speedup vs baseline: 2.3588x; 1.0421x over previous
//
#include <hip/hip_runtime.h>
#include <hip/hip_bf16.h>
#include <math.h>
#include <stdint.h>

#define NT 256
constexpr int Hc = 1024, BOTc = 128, RDc = 48, Nc = 4096;
constexpr int ROWS = 8192;          // B*S
constexpr float INV_SQRT_RD = 0.14433756729740643f;  // 1/sqrt(48)

typedef short bf16x8 __attribute__((ext_vector_type(8)));
typedef float f32x4 __attribute__((ext_vector_type(4)));

// ---------- small helpers ----------
__device__ __forceinline__ uint32_t umin32(uint32_t a, uint32_t b) { return a < b ? a : b; }
__device__ __forceinline__ uint32_t umax32(uint32_t a, uint32_t b) { return a > b ? a : b; }
__device__ __forceinline__ void ce_asc(uint32_t& x, uint32_t& y) {
  uint32_t lo = umin32(x, y), hi = umax32(x, y); x = lo; y = hi;
}
// pack: order-preserving float bits, low 12 bits replaced by slot idx (N=4096)
__device__ __forceinline__ uint32_t pack_score(float s, int slot) {
  uint32_t u = __float_as_uint(s);
  u = (u & 0x80000000u) ? ~u : (u | 0x80000000u);
  return (u & 0xFFFFF000u) | (uint32_t)slot;
}
__device__ __forceinline__ float unpack_score(uint32_t p) {
  uint32_t m = p & 0xFFFFF000u;
  uint32_t f = (m & 0x80000000u) ? (m ^ 0x80000000u) : ~m;
  return __uint_as_float(f);
}
// top-8 of two ascending 8-lists -> ascending, into a[]
__device__ __forceinline__ void merge_top8(uint32_t a[8], const uint32_t b[8]) {
  uint32_t m[8];
#pragma unroll
  for (int i = 0; i < 8; ++i) m[i] = umax32(a[i], b[7 - i]);   // bitonic, holds top-8
  ce_asc(m[0], m[4]); ce_asc(m[1], m[5]); ce_asc(m[2], m[6]); ce_asc(m[3], m[7]);
  ce_asc(m[0], m[2]); ce_asc(m[1], m[3]); ce_asc(m[4], m[6]); ce_asc(m[5], m[7]);
  ce_asc(m[0], m[1]); ce_asc(m[2], m[3]); ce_asc(m[4], m[5]); ce_asc(m[6], m[7]);
#pragma unroll
  for (int i = 0; i < 8; ++i) a[i] = m[i];
}
__device__ __forceinline__ uint16_t bf16bits(float x) {      // RNE
  uint32_t u = __float_as_uint(x);
  return (uint16_t)(((u + 0x7FFFu + ((u >> 16) & 1u)) >> 16) & 0xFFFFu);
}

// ---------- hidden -> bf16 (xb) + per-row variance ----------
__global__ void k_hb(const float* __restrict__ hidden, uint16_t* __restrict__ xb,
                     float* __restrict__ log_var) {
  int row = blockIdx.x;
  float4 v = reinterpret_cast<const float4*>(hidden + (size_t)row * Hc)[threadIdx.x];
  ushort4 h;
  h.x = bf16bits(v.x); h.y = bf16bits(v.y); h.z = bf16bits(v.z); h.w = bf16bits(v.w);
  *reinterpret_cast<ushort4*>(xb + (size_t)row * Hc + threadIdx.x * 4) = h;
  float s = v.x + v.y + v.z + v.w;
  float q = v.x * v.x + v.y * v.y + v.z * v.z + v.w * v.w;
#pragma unroll
  for (int d = 32; d >= 1; d >>= 1) { s += __shfl_down(s, d); q += __shfl_down(q, d); }
  __shared__ float ls[4], lq[4];
  int lane = threadIdx.x & 63, wid = threadIdx.x >> 6;
  if (lane == 0) { ls[wid] = s; lq[wid] = q; }
  __syncthreads();
  if (threadIdx.x == 0) {
    s = ls[0] + ls[1] + ls[2] + ls[3];
    q = lq[0] + lq[1] + lq[2] + lq[3];
    float mean = s * (1.f / Hc);
    float var = q * (1.f / Hc) - mean * mean;
    log_var[row] = log1pf(var);
  }
}

// ---------- global mean of log_var -> 1/(mean+1e-6) ----------
__global__ void k_redsum(const float* __restrict__ log_var, float* __restrict__ stats) {
  float s = 0.f;
  for (int i = threadIdx.x; i < ROWS; i += NT) s += log_var[i];
#pragma unroll
  for (int d = 32; d >= 1; d >>= 1) s += __shfl_down(s, d);
  __shared__ float ls[4];
  int lane = threadIdx.x & 63, wid = threadIdx.x >> 6;
  if (lane == 0) ls[wid] = s;
  __syncthreads();
  if (threadIdx.x == 0) {
    s = ls[0] + ls[1] + ls[2] + ls[3];
    stats[0] = 1.f / (s * (1.f / ROWS) + 1e-6f);
  }
}

// ---------- W48b = bf16(router_w @ q_proj_w)  [48,1024] ----------
__global__ void k_w48(const float* __restrict__ router_w, const float* __restrict__ q_proj_w,
                      uint16_t* __restrict__ W48b) {
  __shared__ float rw[BOTc];
  int j = blockIdx.x;
  for (int d = threadIdx.x; d < BOTc; d += NT) rw[d] = router_w[j * BOTc + d];
  __syncthreads();
  for (int h = threadIdx.x; h < Hc; h += NT) {
    float acc = 0.f;
#pragma unroll 8
    for (int d = 0; d < BOTc; ++d) acc = fmaf(rw[d], q_proj_w[d * Hc + h], acc);
    W48b[j * Hc + h] = bf16bits(acc);
  }
}

// ---------- w1 fp32 -> bf16 ----------
__global__ void k_cvt(const float* __restrict__ src, uint16_t* __restrict__ dst) {
  int i = blockIdx.x * NT + threadIdx.x;
  float4 v = reinterpret_cast<const float4*>(src)[i];
  ushort4 h;
  h.x = bf16bits(v.x); h.y = bf16bits(v.y); h.z = bf16bits(v.z); h.w = bf16bits(v.w);
  reinterpret_cast<ushort4*>(dst)[i] = h;
}

// ---------- rk_b[n][64]: cols 0-47 = (aux_keys[n].router_w[r])/sqrt48, col48 = rel, 49-63 = 0 ----------
__global__ void k_rk(const float* __restrict__ aux_keys, const float* __restrict__ router_w,
                     const float* __restrict__ rel, uint16_t* __restrict__ rk_b) {
  int gid = blockIdx.x * NT + threadIdx.x;           // 4096*48 = 196608 exact
  int n = gid / RDc, r = gid - n * RDc;
  float acc = 0.f;
#pragma unroll 8
  for (int d = 0; d < BOTc; ++d) acc = fmaf(aux_keys[n * BOTc + d], router_w[r * BOTc + d], acc);
  rk_b[(size_t)n * 64 + r] = bf16bits(acc * INV_SQRT_RD);
  if (r < 16) rk_b[(size_t)n * 64 + 48 + r] = (r == 0) ? bf16bits(rel[n]) : (uint16_t)0;
}

// ---------- fused rq + uncertainty GEMM, column-parallel ----------
// 2560 blocks (XCD-swizzled), 4 waves/block. work = rowg (512) x coltile-group (5).
// Each wave: 16 rows x 16 cols, full K=1024.
// coltile ct: 0-15 -> unc cols ct*16.. ; 16-18 -> rq tile ct-16 ; 19 -> rq pad writer.
__global__ __launch_bounds__(256) void k_xw(const uint16_t* __restrict__ xb,
                                            const uint16_t* __restrict__ w1b,
                                            const uint16_t* __restrict__ W48b,
                                            const float* __restrict__ b1,
                                            const float* __restrict__ w2,
                                            float* __restrict__ uncp,
                                            uint16_t* __restrict__ rq_b) {
  int bid = blockIdx.x;
  int wid = (bid & 7) * 320 + (bid >> 3);            // XCD-contiguous work id
  int rowg = wid / 5, cb = wid - rowg * 5;
  int tid = threadIdx.x, wave = tid >> 6, lane = tid & 63;
  int l15 = lane & 15, lg = lane >> 4;
  int ct = cb * 4 + wave;
  int row0 = rowg * 16;

  if (ct == 19) {                                    // rq pad: cols 48-63
    if (lane < 16) {
      uint32_t* p = reinterpret_cast<uint32_t*>(rq_b + (size_t)(row0 + lane) * 64 + 48);
      p[0] = 0x00003F80u; p[1] = 0u; p[2] = 0u; p[3] = 0u;
      p[4] = 0u; p[5] = 0u; p[6] = 0u; p[7] = 0u;
    }
    return;
  }
  const uint16_t* xrow = xb + (size_t)(row0 + l15) * Hc + lg * 8;
  const uint16_t* brow;
  float b1v = 0.f, w2v = 0.f;
  if (ct < 16) {
    int col = ct * 16 + l15;
    brow = w1b + (size_t)col * Hc + lg * 8;
    b1v = b1[col]; w2v = w2[col];
  } else {
    brow = W48b + (size_t)((ct - 16) * 16 + l15) * Hc + lg * 8;
  }
  f32x4 acc = {0.f, 0.f, 0.f, 0.f};
#pragma unroll 4
  for (int kk = 0; kk < Hc; kk += 32) {
    bf16x8 a = *reinterpret_cast<const bf16x8*>(xrow + kk);
    bf16x8 b = *reinterpret_cast<const bf16x8*>(brow + kk);
    acc = __builtin_amdgcn_mfma_f32_16x16x32_bf16(a, b, acc, 0, 0, 0);
  }
  if (ct < 16) {
    float part[4];
#pragma unroll
    for (int r = 0; r < 4; ++r) {
      float x = acc[r] + b1v;
      float g = 0.5f * x * (1.f + erff(x * 0.70710678118654752f));
      part[r] = g * w2v;
    }
#pragma unroll
    for (int d = 1; d < 16; d <<= 1)
#pragma unroll
      for (int r = 0; r < 4; ++r) part[r] += __shfl_xor(part[r], d);
    if (l15 == 0) {
#pragma unroll
      for (int r = 0; r < 4; ++r)
        uncp[(size_t)(row0 + lg * 4 + r) * 16 + ct] = part[r];
    }
  } else {
    int t = ct - 16;
#pragma unroll
    for (int r = 0; r < 4; ++r)
      rq_b[(size_t)(row0 + lg * 4 + r) * 64 + t * 16 + l15] = bf16bits(acc[r]);
  }
}

// ---------- scores via MFMA (swapped operands) + in-register top-8 ----------
// 1024 blocks: rowg = bid>>3 (64 q-rows), range = bid&7 (512 slots = 32 tiles).
__global__ __launch_bounds__(256) void k_scores_mfma(const uint16_t* __restrict__ rq_b,
                                                     const uint16_t* __restrict__ rk_b,
                                                     uint32_t* __restrict__ cand) {
  int tid = threadIdx.x, wave = tid >> 6, lane = tid & 63;
  int l15 = lane & 15, lg = lane >> 4;
  int rowg = blockIdx.x >> 3, range = blockIdx.x & 7;
  int q0 = rowg * 64 + wave * 16;
  const uint16_t* qp = rq_b + (size_t)(q0 + l15) * 64 + lg * 8;
  bf16x8 b1 = *reinterpret_cast<const bf16x8*>(qp);
  bf16x8 b2 = *reinterpret_cast<const bf16x8*>(qp + 32);
  uint32_t top[8];
#pragma unroll
  for (int q = 0; q < 8; ++q) top[q] = 0u;
  int sbase = range * 512;
  for (int t = 0; t < 32; ++t) {
    int s0 = sbase + t * 16;
    const uint16_t* kp = rk_b + (size_t)(s0 + l15) * 64 + lg * 8;
    bf16x8 a1 = *reinterpret_cast<const bf16x8*>(kp);
    bf16x8 a2 = *reinterpret_cast<const bf16x8*>(kp + 32);
    f32x4 acc = {0.f, 0.f, 0.f, 0.f};
    acc = __builtin_amdgcn_mfma_f32_16x16x32_bf16(a1, b1, acc, 0, 0, 0);
    acc = __builtin_amdgcn_mfma_f32_16x16x32_bf16(a2, b2, acc, 0, 0, 0);
#pragma unroll
    for (int r = 0; r < 4; ++r) {
      uint32_t p = pack_score(acc[r], s0 + lg * 4 + r);
      if (p > top[0]) {
        top[0] = p;
        ce_asc(top[0], top[1]); ce_asc(top[1], top[2]); ce_asc(top[2], top[3]);
        ce_asc(top[3], top[4]); ce_asc(top[4], top[5]); ce_asc(top[5], top[6]);
        ce_asc(top[6], top[7]);
      }
    }
  }
  // merge across the 4 lane-groups holding the same q (xor 16, 32)
#pragma unroll
  for (int dd = 16; dd <= 32; dd <<= 1) {
    uint32_t o[8];
#pragma unroll
    for (int q = 0; q < 8; ++q) o[q] = __shfl_xor(top[q], dd);
    merge_top8(top, o);
  }
  if (lg == 0) {
    int row = q0 + l15;
#pragma unroll
    for (int q = 0; q < 8; ++q) cand[((size_t)row * 8 + range) * 8 + q] = top[q];
  }
}

// ---------- merge 8 range-lists, softmax ----------
__global__ void k_topk(const uint32_t* __restrict__ cand, float* __restrict__ topw,
                       int* __restrict__ topidx) {
  int row = blockIdx.x * NT + threadIdx.x;
  uint32_t l[8][8];
  const uint32_t* c = cand + (size_t)row * 64;
#pragma unroll
  for (int g = 0; g < 8; ++g)
#pragma unroll
    for (int q = 0; q < 8; ++q) l[g][q] = c[g * 8 + q];
  merge_top8(l[0], l[1]); merge_top8(l[2], l[3]);
  merge_top8(l[4], l[5]); merge_top8(l[6], l[7]);
  merge_top8(l[0], l[2]); merge_top8(l[4], l[6]);
  merge_top8(l[0], l[4]);                            // l[0] = global top-8 (asc)
  float sc[8];
#pragma unroll
  for (int q = 0; q < 8; ++q) sc[q] = unpack_score(l[0][q]);
  float mx = sc[7];
  float e[8]; float sum = 0.f;
#pragma unroll
  for (int q = 0; q < 8; ++q) { e[q] = expf(sc[q] - mx); sum += e[q]; }
  float inv = 1.f / sum;
#pragma unroll
  for (int q = 0; q < 8; ++q) {
    topw[(size_t)row * 8 + q] = e[7 - q] * inv;
    topidx[(size_t)row * 8 + q] = (int)(l[0][7 - q] & 0xFFFu);
  }
}

// ---------- gather + gate + output (fp32) ----------
__global__ __launch_bounds__(256) void k_final(const float* __restrict__ hidden,
                                               const float* __restrict__ aux_values,
                                               const float* __restrict__ topw,
                                               const int* __restrict__ topidx,
                                               const float* __restrict__ log_var,
                                               const float* __restrict__ uncp,
                                               const float* __restrict__ stats,
                                               const float* __restrict__ b2,
                                               const float* __restrict__ gw,
                                               const float* __restrict__ gb,
                                               float* __restrict__ out) {
  int row = blockIdx.x;
  int tid = threadIdx.x;
  __shared__ float ws_[8]; __shared__ int wi_[8]; __shared__ float sgate;
  if (tid < 8) { ws_[tid] = topw[(size_t)row * 8 + tid]; wi_[tid] = topidx[(size_t)row * 8 + tid]; }
  if (tid < 16) {
    float lv = uncp[(size_t)row * 16 + tid];
#pragma unroll
    for (int d = 1; d < 16; d <<= 1) lv += __shfl_xor(lv, d);
    if (tid == 0) {
      float learned = lv + b2[0];
      float nv = log_var[row] * stats[0];
      float sig = 1.f / (1.f + expf(-learned));
      float u = nv * 0.5f + sig * 2.5f;
      u = fminf(fmaxf(u, 0.f), 5.f);
      sgate = 1.f / (1.f + expf(-(gw[0] * u + gb[0])));
    }
  }
  __syncthreads();
  int h0 = tid * 4;
  float4 hv = *reinterpret_cast<const float4*>(hidden + (size_t)row * Hc + h0);
  float ax = 0.f, ay = 0.f, az = 0.f, aw = 0.f;
#pragma unroll
  for (int k = 0; k < 8; ++k) {
    float w = ws_[k];
    float4 v = *reinterpret_cast<const float4*>(aux_values + (size_t)wi_[k] * Hc + h0);
    ax = fmaf(w, v.x, ax); ay = fmaf(w, v.y, ay); az = fmaf(w, v.z, az); aw = fmaf(w, v.w, aw);
  }
  float g = sgate;
  float4 o;
  o.x = hv.x + g * ax; o.y = hv.y + g * ay; o.z = hv.z + g * az; o.w = hv.w + g * aw;
  *reinterpret_cast<float4*>(out + (size_t)row * Hc + h0) = o;
}

extern "C" void kernel_launch(void* const* d_in, const int* in_sizes, int n_in,
                              void* d_out, int out_size, void* d_ws, size_t ws_size,
                              hipStream_t stream) {
  const float* hidden     = (const float*)d_in[0];
  const float* q_proj_w   = (const float*)d_in[1];
  const float* router_w   = (const float*)d_in[2];
  const float* aux_keys   = (const float*)d_in[3];
  const float* aux_values = (const float*)d_in[4];
  const float* rel        = (const float*)d_in[5];
  const float* unc_w1     = (const float*)d_in[6];
  const float* unc_b1     = (const float*)d_in[7];
  const float* unc_w2     = (const float*)d_in[8];
  const float* unc_b2     = (const float*)d_in[9];
  const float* gate_w1    = (const float*)d_in[10];
  const float* gate_bias  = (const float*)d_in[11];
  float* out = (float*)d_out;

  uint8_t* w = (uint8_t*)d_ws;              // ~22 MB used
  uint16_t* xb    = (uint16_t*)w;                 w += (size_t)ROWS * Hc * 2;     // 16 MB
  uint16_t* w1b   = (uint16_t*)w;                 w += (size_t)256 * Hc * 2;      // 512 KB
  uint16_t* W48b  = (uint16_t*)w;                 w += (size_t)48 * Hc * 2;       // 96 KB
  uint16_t* rq_b  = (uint16_t*)w;                 w += (size_t)ROWS * 64 * 2;     // 1 MB
  uint16_t* rk_b  = (uint16_t*)w;                 w += (size_t)Nc * 64 * 2;       // 512 KB
  float* log_var  = (float*)w;                    w += (size_t)ROWS * 4;
  float* uncp     = (float*)w;                    w += (size_t)ROWS * 16 * 4;     // 512 KB
  float* stats    = (float*)w;                    w += 256;
  uint32_t* cand  = (uint32_t*)w;                 w += (size_t)ROWS * 64 * 4;     // 2 MB
  float* topw     = (float*)w;                    w += (size_t)ROWS * 8 * 4;
  int* topidx     = (int*)w;                      w += (size_t)ROWS * 8 * 4;

  k_w48<<<48, NT, 0, stream>>>(router_w, q_proj_w, W48b);
  k_cvt<<<256, NT, 0, stream>>>(unc_w1, w1b);
  k_rk<<<768, NT, 0, stream>>>(aux_keys, router_w, rel, rk_b);
  k_hb<<<ROWS, NT, 0, stream>>>(hidden, xb, log_var);
  k_redsum<<<1, NT, 0, stream>>>(log_var, stats);
  k_xw<<<2560, NT, 0, stream>>>(xb, w1b, W48b, unc_b1, unc_w2, uncp, rq_b);
  k_scores_mfma<<<1024, NT, 0, stream>>>(rq_b, rk_b, cand);
  k_topk<<<ROWS / NT, NT, 0, stream>>>(cand, topw, topidx);
  k_final<<<ROWS, NT, 0, stream>>>(hidden, aux_values, topw, topidx, log_var, uncp,
                                   stats, unc_b2, gate_w1, gate_bias, out);
}

// Round 5
// 162.987 us; speedup vs baseline: 2.7865x; 1.1813x over previous
//
#include <hip/hip_runtime.h>
#include <hip/hip_bf16.h>
#include <math.h>
#include <stdint.h>

#define NT 256
constexpr int Hc = 1024, BOTc = 128, RDc = 48, Nc = 4096;
constexpr int ROWS = 8192;          // B*S
constexpr float INV_SQRT_RD = 0.14433756729740643f;  // 1/sqrt(48)

typedef short bf16x8 __attribute__((ext_vector_type(8)));
typedef float f32x4 __attribute__((ext_vector_type(4)));

// ---------- small helpers ----------
__device__ __forceinline__ uint32_t umin32(uint32_t a, uint32_t b) { return a < b ? a : b; }
__device__ __forceinline__ uint32_t umax32(uint32_t a, uint32_t b) { return a > b ? a : b; }
__device__ __forceinline__ void ce_asc(uint32_t& x, uint32_t& y) {
  uint32_t lo = umin32(x, y), hi = umax32(x, y); x = lo; y = hi;
}
__device__ __forceinline__ uint32_t pack_score(float s, int slot) {
  uint32_t u = __float_as_uint(s);
  u = (u & 0x80000000u) ? ~u : (u | 0x80000000u);
  return (u & 0xFFFFF000u) | (uint32_t)slot;
}
__device__ __forceinline__ float unpack_score(uint32_t p) {
  uint32_t m = p & 0xFFFFF000u;
  uint32_t f = (m & 0x80000000u) ? (m ^ 0x80000000u) : ~m;
  return __uint_as_float(f);
}
__device__ __forceinline__ void merge_top8(uint32_t a[8], const uint32_t b[8]) {
  uint32_t m[8];
#pragma unroll
  for (int i = 0; i < 8; ++i) m[i] = umax32(a[i], b[7 - i]);
  ce_asc(m[0], m[4]); ce_asc(m[1], m[5]); ce_asc(m[2], m[6]); ce_asc(m[3], m[7]);
  ce_asc(m[0], m[2]); ce_asc(m[1], m[3]); ce_asc(m[4], m[6]); ce_asc(m[5], m[7]);
  ce_asc(m[0], m[1]); ce_asc(m[2], m[3]); ce_asc(m[4], m[5]); ce_asc(m[6], m[7]);
#pragma unroll
  for (int i = 0; i < 8; ++i) a[i] = m[i];
}
__device__ __forceinline__ uint16_t bf16bits(float x) {      // RNE
  uint32_t u = __float_as_uint(x);
  return (uint16_t)(((u + 0x7FFFu + ((u >> 16) & 1u)) >> 16) & 0xFFFFu);
}
__device__ __forceinline__ float bf2f(uint16_t h) {
  return __uint_as_float((uint32_t)h << 16);
}

// ---------- fused fp32->bf16 converts: unc_w1 (256K) + aux_values (4.19M) ----------
__global__ void k_prep(const float* __restrict__ w1, const float* __restrict__ aux,
                       uint16_t* __restrict__ w1b, uint16_t* __restrict__ avb) {
  int i = blockIdx.x * NT + threadIdx.x;             // float4 index
  const int W1Q = 256 * Hc / 4;                      // 65536
  float4 v;
  ushort4 h;
  if (i < W1Q) {
    v = reinterpret_cast<const float4*>(w1)[i];
    h.x = bf16bits(v.x); h.y = bf16bits(v.y); h.z = bf16bits(v.z); h.w = bf16bits(v.w);
    reinterpret_cast<ushort4*>(w1b)[i] = h;
  } else {
    int j = i - W1Q;
    v = reinterpret_cast<const float4*>(aux)[j];
    h.x = bf16bits(v.x); h.y = bf16bits(v.y); h.z = bf16bits(v.z); h.w = bf16bits(v.w);
    reinterpret_cast<ushort4*>(avb)[j] = h;
  }
}

// ---------- hidden -> bf16 (xb) + per-row variance ----------
__global__ void k_hb(const float* __restrict__ hidden, uint16_t* __restrict__ xb,
                     float* __restrict__ log_var) {
  int row = blockIdx.x;
  float4 v = reinterpret_cast<const float4*>(hidden + (size_t)row * Hc)[threadIdx.x];
  ushort4 h;
  h.x = bf16bits(v.x); h.y = bf16bits(v.y); h.z = bf16bits(v.z); h.w = bf16bits(v.w);
  *reinterpret_cast<ushort4*>(xb + (size_t)row * Hc + threadIdx.x * 4) = h;
  float s = v.x + v.y + v.z + v.w;
  float q = v.x * v.x + v.y * v.y + v.z * v.z + v.w * v.w;
#pragma unroll
  for (int d = 32; d >= 1; d >>= 1) { s += __shfl_down(s, d); q += __shfl_down(q, d); }
  __shared__ float ls[4], lq[4];
  int lane = threadIdx.x & 63, wid = threadIdx.x >> 6;
  if (lane == 0) { ls[wid] = s; lq[wid] = q; }
  __syncthreads();
  if (threadIdx.x == 0) {
    s = ls[0] + ls[1] + ls[2] + ls[3];
    q = lq[0] + lq[1] + lq[2] + lq[3];
    float mean = s * (1.f / Hc);
    float var = q * (1.f / Hc) - mean * mean;
    log_var[row] = log1pf(var);
  }
}

// ---------- global mean of log_var -> 1/(mean+1e-6) ----------
__global__ __launch_bounds__(1024) void k_redsum(const float* __restrict__ log_var,
                                                 float* __restrict__ stats) {
  float s = 0.f;
  for (int i = threadIdx.x; i < ROWS; i += 1024) s += log_var[i];
#pragma unroll
  for (int d = 32; d >= 1; d >>= 1) s += __shfl_down(s, d);
  __shared__ float ls[16];
  int lane = threadIdx.x & 63, wid = threadIdx.x >> 6;
  if (lane == 0) ls[wid] = s;
  __syncthreads();
  if (threadIdx.x == 0) {
    s = 0.f;
#pragma unroll
    for (int i = 0; i < 16; ++i) s += ls[i];
    stats[0] = 1.f / (s * (1.f / ROWS) + 1e-6f);
  }
}

// ---------- W48b = bf16(router_w @ q_proj_w)  [64,1024], rows 48-63 zero ----------
__global__ void k_w48(const float* __restrict__ router_w, const float* __restrict__ q_proj_w,
                      uint16_t* __restrict__ W48b) {
  __shared__ float rw[BOTc];
  int j = blockIdx.x;
  if (j >= RDc) {
    for (int h = threadIdx.x; h < Hc; h += NT) W48b[(size_t)j * Hc + h] = 0;
    return;
  }
  for (int d = threadIdx.x; d < BOTc; d += NT) rw[d] = router_w[j * BOTc + d];
  __syncthreads();
  for (int h = threadIdx.x; h < Hc; h += NT) {
    float acc = 0.f;
#pragma unroll 8
    for (int d = 0; d < BOTc; ++d) acc = fmaf(rw[d], q_proj_w[d * Hc + h], acc);
    W48b[(size_t)j * Hc + h] = bf16bits(acc);
  }
}

// ---------- rk_b[n][64]: cols 0-47 = (aux_keys[n].router_w[r])/sqrt48, col48 = rel, 49-63 = 0 ----------
__global__ void k_rk(const float* __restrict__ aux_keys, const float* __restrict__ router_w,
                     const float* __restrict__ rel, uint16_t* __restrict__ rk_b) {
  int gid = blockIdx.x * NT + threadIdx.x;           // 4096*48
  int n = gid / RDc, r = gid - n * RDc;
  float acc = 0.f;
#pragma unroll 8
  for (int d = 0; d < BOTc; ++d) acc = fmaf(aux_keys[n * BOTc + d], router_w[r * BOTc + d], acc);
  rk_b[(size_t)n * 64 + r] = bf16bits(acc * INV_SQRT_RD);
  if (r < 16) rk_b[(size_t)n * 64 + 48 + r] = (r == 0) ? bf16bits(rel[n]) : (uint16_t)0;
}

// ---------- fused rq + uncertainty GEMM: 32x32 register-blocked ----------
// 640 blocks (8x80 XCD-bijective), 4 waves/block; work = rowg(256 x 32rows) x cg(10 x 32cols).
// cg 0-7: unc cols cg*32; cg 8-9: rq cols (cg-8)*32 (W48b zero-padded; col48 -> 1.0).
__global__ __launch_bounds__(256) void k_xw(const uint16_t* __restrict__ xb,
                                            const uint16_t* __restrict__ w1b,
                                            const uint16_t* __restrict__ W48b,
                                            const float* __restrict__ b1,
                                            const float* __restrict__ w2,
                                            float* __restrict__ uncp,
                                            uint16_t* __restrict__ rq_b) {
  int bid = blockIdx.x;
  int wid4 = (bid & 7) * 80 + (bid >> 3);            // XCD-contiguous
  int tid = threadIdx.x, wave = tid >> 6, lane = tid & 63;
  int w_id = wid4 * 4 + wave;
  int rowg = w_id / 10, cg = w_id - rowg * 10;
  int l15 = lane & 15, lg = lane >> 4;
  int row0 = rowg * 32;
  const uint16_t* wbase = (cg < 8) ? (w1b + (size_t)(cg * 32) * Hc)
                                   : (W48b + (size_t)((cg - 8) * 32) * Hc);
  const uint16_t* a0p = xb + (size_t)(row0 + l15) * Hc + lg * 8;
  const uint16_t* a1p = a0p + (size_t)16 * Hc;
  const uint16_t* b0p = wbase + (size_t)l15 * Hc + lg * 8;
  const uint16_t* b1p = b0p + (size_t)16 * Hc;
  f32x4 acc00 = {0.f,0.f,0.f,0.f}, acc01 = {0.f,0.f,0.f,0.f};
  f32x4 acc10 = {0.f,0.f,0.f,0.f}, acc11 = {0.f,0.f,0.f,0.f};
#pragma unroll 4
  for (int kk = 0; kk < Hc; kk += 32) {
    bf16x8 a0 = *reinterpret_cast<const bf16x8*>(a0p + kk);
    bf16x8 a1 = *reinterpret_cast<const bf16x8*>(a1p + kk);
    bf16x8 b0 = *reinterpret_cast<const bf16x8*>(b0p + kk);
    bf16x8 bb = *reinterpret_cast<const bf16x8*>(b1p + kk);
    acc00 = __builtin_amdgcn_mfma_f32_16x16x32_bf16(a0, b0, acc00, 0, 0, 0);
    acc01 = __builtin_amdgcn_mfma_f32_16x16x32_bf16(a0, bb, acc01, 0, 0, 0);
    acc10 = __builtin_amdgcn_mfma_f32_16x16x32_bf16(a1, b0, acc10, 0, 0, 0);
    acc11 = __builtin_amdgcn_mfma_f32_16x16x32_bf16(a1, bb, acc11, 0, 0, 0);
  }
  if (cg < 8) {
    int c0 = cg * 32;
    float b1v0 = b1[c0 + l15],      w2v0 = w2[c0 + l15];
    float b1v1 = b1[c0 + 16 + l15], w2v1 = w2[c0 + 16 + l15];
    float part0[4], part1[4];
#pragma unroll
    for (int r = 0; r < 4; ++r) {
      float x00 = acc00[r] + b1v0, x01 = acc01[r] + b1v1;
      float x10 = acc10[r] + b1v0, x11 = acc11[r] + b1v1;
      float g00 = 0.5f * x00 * (1.f + erff(x00 * 0.70710678118654752f));
      float g01 = 0.5f * x01 * (1.f + erff(x01 * 0.70710678118654752f));
      float g10 = 0.5f * x10 * (1.f + erff(x10 * 0.70710678118654752f));
      float g11 = 0.5f * x11 * (1.f + erff(x11 * 0.70710678118654752f));
      part0[r] = fmaf(g00, w2v0, g01 * w2v1);
      part1[r] = fmaf(g10, w2v0, g11 * w2v1);
    }
#pragma unroll
    for (int d = 1; d < 16; d <<= 1)
#pragma unroll
      for (int r = 0; r < 4; ++r) {
        part0[r] += __shfl_xor(part0[r], d);
        part1[r] += __shfl_xor(part1[r], d);
      }
    if (l15 == 0) {
#pragma unroll
      for (int r = 0; r < 4; ++r) {
        uncp[(size_t)(row0 + lg * 4 + r) * 8 + cg] = part0[r];
        uncp[(size_t)(row0 + 16 + lg * 4 + r) * 8 + cg] = part1[r];
      }
    }
  } else {
    int c0 = (cg - 8) * 32;
    int colA = c0 + l15, colB = c0 + 16 + l15;
#pragma unroll
    for (int r = 0; r < 4; ++r) {
      uint16_t vA = bf16bits(acc00[r]);
      uint16_t vB = bf16bits(acc01[r]); if (colB == 48) vB = 0x3F80u;
      uint16_t uA = bf16bits(acc10[r]);
      uint16_t uB = bf16bits(acc11[r]); if (colB == 48) uB = 0x3F80u;
      rq_b[(size_t)(row0 + lg * 4 + r) * 64 + colA] = vA;
      rq_b[(size_t)(row0 + lg * 4 + r) * 64 + colB] = vB;
      rq_b[(size_t)(row0 + 16 + lg * 4 + r) * 64 + colA] = uA;
      rq_b[(size_t)(row0 + 16 + lg * 4 + r) * 64 + colB] = uB;
    }
  }
}

// ---------- scores via MFMA (swapped operands) + in-register top-8 ----------
// 1024 blocks: rowg = bid>>3 (64 q-rows), range = bid&7 (512 slots).
__global__ __launch_bounds__(256) void k_scores_mfma(const uint16_t* __restrict__ rq_b,
                                                     const uint16_t* __restrict__ rk_b,
                                                     uint32_t* __restrict__ cand) {
  int tid = threadIdx.x, wave = tid >> 6, lane = tid & 63;
  int l15 = lane & 15, lg = lane >> 4;
  int rowg = blockIdx.x >> 3, range = blockIdx.x & 7;
  int q0 = rowg * 64 + wave * 16;
  const uint16_t* qp = rq_b + (size_t)(q0 + l15) * 64 + lg * 8;
  bf16x8 qf1 = *reinterpret_cast<const bf16x8*>(qp);
  bf16x8 qf2 = *reinterpret_cast<const bf16x8*>(qp + 32);
  uint32_t top[8];
#pragma unroll
  for (int q = 0; q < 8; ++q) top[q] = 0u;
  int sbase = range * 512;
  for (int t = 0; t < 32; t += 2) {
    int s0 = sbase + t * 16;
    const uint16_t* kp0 = rk_b + (size_t)(s0 + l15) * 64 + lg * 8;
    const uint16_t* kp1 = kp0 + 16 * 64;
    bf16x8 a1 = *reinterpret_cast<const bf16x8*>(kp0);
    bf16x8 a2 = *reinterpret_cast<const bf16x8*>(kp0 + 32);
    bf16x8 a3 = *reinterpret_cast<const bf16x8*>(kp1);
    bf16x8 a4 = *reinterpret_cast<const bf16x8*>(kp1 + 32);
    f32x4 acc0 = {0.f,0.f,0.f,0.f}, acc1 = {0.f,0.f,0.f,0.f};
    acc0 = __builtin_amdgcn_mfma_f32_16x16x32_bf16(a1, qf1, acc0, 0, 0, 0);
    acc1 = __builtin_amdgcn_mfma_f32_16x16x32_bf16(a3, qf1, acc1, 0, 0, 0);
    acc0 = __builtin_amdgcn_mfma_f32_16x16x32_bf16(a2, qf2, acc0, 0, 0, 0);
    acc1 = __builtin_amdgcn_mfma_f32_16x16x32_bf16(a4, qf2, acc1, 0, 0, 0);
#pragma unroll
    for (int r = 0; r < 4; ++r) {
      uint32_t p = pack_score(acc0[r], s0 + lg * 4 + r);
      if (p > top[0]) {
        top[0] = p;
        ce_asc(top[0], top[1]); ce_asc(top[1], top[2]); ce_asc(top[2], top[3]);
        ce_asc(top[3], top[4]); ce_asc(top[4], top[5]); ce_asc(top[5], top[6]);
        ce_asc(top[6], top[7]);
      }
    }
#pragma unroll
    for (int r = 0; r < 4; ++r) {
      uint32_t p = pack_score(acc1[r], s0 + 16 + lg * 4 + r);
      if (p > top[0]) {
        top[0] = p;
        ce_asc(top[0], top[1]); ce_asc(top[1], top[2]); ce_asc(top[2], top[3]);
        ce_asc(top[3], top[4]); ce_asc(top[4], top[5]); ce_asc(top[5], top[6]);
        ce_asc(top[6], top[7]);
      }
    }
  }
#pragma unroll
  for (int dd = 16; dd <= 32; dd <<= 1) {
    uint32_t o[8];
#pragma unroll
    for (int q = 0; q < 8; ++q) o[q] = __shfl_xor(top[q], dd);
    merge_top8(top, o);
  }
  if (lg == 0) {
    int row = q0 + l15;
#pragma unroll
    for (int q = 0; q < 8; ++q) cand[((size_t)row * 8 + range) * 8 + q] = top[q];
  }
}

// ---------- merge ranges + softmax + gate + gather (bf16 table) + output ----------
__global__ __launch_bounds__(256) void k_final(const float* __restrict__ hidden,
                                               const uint16_t* __restrict__ avb,
                                               const uint32_t* __restrict__ cand,
                                               const float* __restrict__ log_var,
                                               const float* __restrict__ uncp,
                                               const float* __restrict__ stats,
                                               const float* __restrict__ b2,
                                               const float* __restrict__ gw,
                                               const float* __restrict__ gb,
                                               float* __restrict__ out) {
  int row = blockIdx.x;
  int tid = threadIdx.x;
  __shared__ float ws_[8]; __shared__ int wi_[8]; __shared__ float sgate;
  if (tid < 64) {
    int lane = tid;
    uint32_t l[8];
    float up = 0.f;
    if (lane < 8) {
      const uint32_t* c = cand + (size_t)row * 64 + lane * 8;
#pragma unroll
      for (int q = 0; q < 8; ++q) l[q] = c[q];
      up = uncp[(size_t)row * 8 + lane];
    } else {
#pragma unroll
      for (int q = 0; q < 8; ++q) l[q] = 0u;
    }
#pragma unroll
    for (int d = 1; d < 8; d <<= 1) {
      uint32_t o[8];
#pragma unroll
      for (int q = 0; q < 8; ++q) o[q] = __shfl_xor(l[q], d);
      merge_top8(l, o);
      up += __shfl_xor(up, d);
    }
    if (lane == 0) {
      float sc[8];
#pragma unroll
      for (int q = 0; q < 8; ++q) sc[q] = unpack_score(l[q]);
      float mx = sc[7];
      float e[8]; float sum = 0.f;
#pragma unroll
      for (int q = 0; q < 8; ++q) { e[q] = expf(sc[q] - mx); sum += e[q]; }
      float inv = 1.f / sum;
#pragma unroll
      for (int q = 0; q < 8; ++q) { ws_[q] = e[q] * inv; wi_[q] = (int)(l[q] & 0xFFFu); }
      float learned = up + b2[0];
      float nv = log_var[row] * stats[0];
      float sig = 1.f / (1.f + expf(-learned));
      float u = nv * 0.5f + sig * 2.5f;
      u = fminf(fmaxf(u, 0.f), 5.f);
      sgate = 1.f / (1.f + expf(-(gw[0] * u + gb[0])));
    }
  }
  __syncthreads();
  int h0 = tid * 4;
  float4 hv = *reinterpret_cast<const float4*>(hidden + (size_t)row * Hc + h0);
  float ax = 0.f, ay = 0.f, az = 0.f, aw = 0.f;
#pragma unroll
  for (int k = 0; k < 8; ++k) {
    float w = ws_[k];
    ushort4 v = *reinterpret_cast<const ushort4*>(avb + (size_t)wi_[k] * Hc + h0);
    ax = fmaf(w, bf2f(v.x), ax); ay = fmaf(w, bf2f(v.y), ay);
    az = fmaf(w, bf2f(v.z), az); aw = fmaf(w, bf2f(v.w), aw);
  }
  float g = sgate;
  float4 o;
  o.x = hv.x + g * ax; o.y = hv.y + g * ay; o.z = hv.z + g * az; o.w = hv.w + g * aw;
  *reinterpret_cast<float4*>(out + (size_t)row * Hc + h0) = o;
}

extern "C" void kernel_launch(void* const* d_in, const int* in_sizes, int n_in,
                              void* d_out, int out_size, void* d_ws, size_t ws_size,
                              hipStream_t stream) {
  const float* hidden     = (const float*)d_in[0];
  const float* q_proj_w   = (const float*)d_in[1];
  const float* router_w   = (const float*)d_in[2];
  const float* aux_keys   = (const float*)d_in[3];
  const float* aux_values = (const float*)d_in[4];
  const float* rel        = (const float*)d_in[5];
  const float* unc_w1     = (const float*)d_in[6];
  const float* unc_b1     = (const float*)d_in[7];
  const float* unc_w2     = (const float*)d_in[8];
  const float* unc_b2     = (const float*)d_in[9];
  const float* gate_w1    = (const float*)d_in[10];
  const float* gate_bias  = (const float*)d_in[11];
  float* out = (float*)d_out;

  uint8_t* w = (uint8_t*)d_ws;              // ~28.5 MB used
  uint16_t* xb    = (uint16_t*)w;                 w += (size_t)ROWS * Hc * 2;     // 16 MB
  uint16_t* w1b   = (uint16_t*)w;                 w += (size_t)256 * Hc * 2;      // 512 KB
  uint16_t* avb   = (uint16_t*)w;                 w += (size_t)Nc * Hc * 2;       // 8 MB
  uint16_t* W48b  = (uint16_t*)w;                 w += (size_t)64 * Hc * 2;       // 128 KB
  uint16_t* rq_b  = (uint16_t*)w;                 w += (size_t)ROWS * 64 * 2;     // 1 MB
  uint16_t* rk_b  = (uint16_t*)w;                 w += (size_t)Nc * 64 * 2;       // 512 KB
  float* log_var  = (float*)w;                    w += (size_t)ROWS * 4;
  float* uncp     = (float*)w;                    w += (size_t)ROWS * 8 * 4;      // 256 KB
  float* stats    = (float*)w;                    w += 256;
  uint32_t* cand  = (uint32_t*)w;                 w += (size_t)ROWS * 64 * 4;     // 2 MB

  k_prep<<<4352, NT, 0, stream>>>(unc_w1, aux_values, w1b, avb);
  k_w48<<<64, NT, 0, stream>>>(router_w, q_proj_w, W48b);
  k_rk<<<768, NT, 0, stream>>>(aux_keys, router_w, rel, rk_b);
  k_hb<<<ROWS, NT, 0, stream>>>(hidden, xb, log_var);
  k_redsum<<<1, 1024, 0, stream>>>(log_var, stats);
  k_xw<<<640, NT, 0, stream>>>(xb, w1b, W48b, unc_b1, unc_w2, uncp, rq_b);
  k_scores_mfma<<<1024, NT, 0, stream>>>(rq_b, rk_b, cand);
  k_final<<<ROWS, NT, 0, stream>>>(hidden, avb, cand, log_var, uncp,
                                   stats, unc_b2, gate_w1, gate_bias, out);
}

// Round 6
// 147.824 us; speedup vs baseline: 3.0724x; 1.1026x over previous
//
#include <hip/hip_runtime.h>
#include <hip/hip_bf16.h>
#include <math.h>
#include <stdint.h>

#define NT 256
constexpr int Hc = 1024, BOTc = 128, RDc = 48, Nc = 4096;
constexpr int ROWS = 8192;          // B*S
constexpr float INV_SQRT_RD = 0.14433756729740643f;  // 1/sqrt(48)

typedef short bf16x8 __attribute__((ext_vector_type(8)));
typedef float f32x4 __attribute__((ext_vector_type(4)));

// ---------- small helpers ----------
__device__ __forceinline__ uint32_t umin32(uint32_t a, uint32_t b) { return a < b ? a : b; }
__device__ __forceinline__ uint32_t umax32(uint32_t a, uint32_t b) { return a > b ? a : b; }
__device__ __forceinline__ void ce_asc(uint32_t& x, uint32_t& y) {
  uint32_t lo = umin32(x, y), hi = umax32(x, y); x = lo; y = hi;
}
__device__ __forceinline__ uint32_t pack_score(float s, int slot) {
  uint32_t u = __float_as_uint(s);
  u = (u & 0x80000000u) ? ~u : (u | 0x80000000u);
  return (u & 0xFFFFF000u) | (uint32_t)slot;
}
__device__ __forceinline__ float unpack_score(uint32_t p) {
  uint32_t m = p & 0xFFFFF000u;
  uint32_t f = (m & 0x80000000u) ? (m ^ 0x80000000u) : ~m;
  return __uint_as_float(f);
}
__device__ __forceinline__ void merge_top8(uint32_t a[8], const uint32_t b[8]) {
  uint32_t m[8];
#pragma unroll
  for (int i = 0; i < 8; ++i) m[i] = umax32(a[i], b[7 - i]);
  ce_asc(m[0], m[4]); ce_asc(m[1], m[5]); ce_asc(m[2], m[6]); ce_asc(m[3], m[7]);
  ce_asc(m[0], m[2]); ce_asc(m[1], m[3]); ce_asc(m[4], m[6]); ce_asc(m[5], m[7]);
  ce_asc(m[0], m[1]); ce_asc(m[2], m[3]); ce_asc(m[4], m[5]); ce_asc(m[6], m[7]);
#pragma unroll
  for (int i = 0; i < 8; ++i) a[i] = m[i];
}
__device__ __forceinline__ void top8_insert(uint32_t top[8], uint32_t p) {
  if (p > top[0]) {
    top[0] = p;
    ce_asc(top[0], top[1]); ce_asc(top[1], top[2]); ce_asc(top[2], top[3]);
    ce_asc(top[3], top[4]); ce_asc(top[4], top[5]); ce_asc(top[5], top[6]);
    ce_asc(top[6], top[7]);
  }
}
__device__ __forceinline__ uint16_t bf16bits(float x) {      // RNE
  uint32_t u = __float_as_uint(x);
  return (uint16_t)(((u + 0x7FFFu + ((u >> 16) & 1u)) >> 16) & 0xFFFFu);
}
__device__ __forceinline__ float bf2f(uint16_t h) {
  return __uint_as_float((uint32_t)h << 16);
}

// ---------- fused prep: cvt(w1,aux) + hb(variance+xb) + w48 + rk ----------
constexpr int G_CVT = 4352;        // (256*1024 + 4096*1024)/4/256
constexpr int G_HB  = 8192;
constexpr int G_W48 = 64;
constexpr int G_RK  = 768;
__global__ __launch_bounds__(256) void k_prep_all(
    const float* __restrict__ hidden, const float* __restrict__ q_proj_w,
    const float* __restrict__ router_w, const float* __restrict__ aux_keys,
    const float* __restrict__ aux_values, const float* __restrict__ rel,
    const float* __restrict__ unc_w1,
    uint16_t* __restrict__ xb, float* __restrict__ log_var,
    uint16_t* __restrict__ w1b, uint16_t* __restrict__ avb,
    uint16_t* __restrict__ W48b, uint16_t* __restrict__ rk_b) {
  __shared__ float smem[136];
  int bid = blockIdx.x;
  int tid = threadIdx.x;
  if (bid < G_CVT) {
    // fp32 -> bf16 converts: unc_w1 then aux_values
    int i = bid * NT + tid;
    const int W1Q = 256 * Hc / 4;
    float4 v; ushort4 h;
    if (i < W1Q) {
      v = reinterpret_cast<const float4*>(unc_w1)[i];
      h.x = bf16bits(v.x); h.y = bf16bits(v.y); h.z = bf16bits(v.z); h.w = bf16bits(v.w);
      reinterpret_cast<ushort4*>(w1b)[i] = h;
    } else {
      int j = i - W1Q;
      v = reinterpret_cast<const float4*>(aux_values)[j];
      h.x = bf16bits(v.x); h.y = bf16bits(v.y); h.z = bf16bits(v.z); h.w = bf16bits(v.w);
      reinterpret_cast<ushort4*>(avb)[j] = h;
    }
    return;
  }
  bid -= G_CVT;
  if (bid < G_HB) {
    // hidden -> xb + variance
    int row = bid;
    float4 v = reinterpret_cast<const float4*>(hidden + (size_t)row * Hc)[tid];
    ushort4 h;
    h.x = bf16bits(v.x); h.y = bf16bits(v.y); h.z = bf16bits(v.z); h.w = bf16bits(v.w);
    *reinterpret_cast<ushort4*>(xb + (size_t)row * Hc + tid * 4) = h;
    float s = v.x + v.y + v.z + v.w;
    float q = v.x * v.x + v.y * v.y + v.z * v.z + v.w * v.w;
#pragma unroll
    for (int d = 32; d >= 1; d >>= 1) { s += __shfl_down(s, d); q += __shfl_down(q, d); }
    int lane = tid & 63, wid = tid >> 6;
    if (lane == 0) { smem[wid] = s; smem[4 + wid] = q; }
    __syncthreads();
    if (tid == 0) {
      s = smem[0] + smem[1] + smem[2] + smem[3];
      q = smem[4] + smem[5] + smem[6] + smem[7];
      float mean = s * (1.f / Hc);
      float var = q * (1.f / Hc) - mean * mean;
      log_var[row] = log1pf(var);
    }
    return;
  }
  bid -= G_HB;
  if (bid < G_W48) {
    // W48b[64][1024], rows 48-63 zero
    int j = bid;
    if (j >= RDc) {
      for (int hh = tid; hh < Hc; hh += NT) W48b[(size_t)j * Hc + hh] = 0;
      return;
    }
    for (int d = tid; d < BOTc; d += NT) smem[8 + d] = router_w[j * BOTc + d];
    __syncthreads();
    for (int hh = tid; hh < Hc; hh += NT) {
      float acc = 0.f;
#pragma unroll 8
      for (int d = 0; d < BOTc; ++d) acc = fmaf(smem[8 + d], q_proj_w[d * Hc + hh], acc);
      W48b[(size_t)j * Hc + hh] = bf16bits(acc);
    }
    return;
  }
  bid -= G_W48;
  {
    // rk_b[n][64]
    int gid = bid * NT + tid;
    int n = gid / RDc, r = gid - n * RDc;
    float acc = 0.f;
#pragma unroll 8
    for (int d = 0; d < BOTc; ++d)
      acc = fmaf(aux_keys[n * BOTc + d], router_w[r * BOTc + d], acc);
    rk_b[(size_t)n * 64 + r] = bf16bits(acc * INV_SQRT_RD);
    if (r < 16) rk_b[(size_t)n * 64 + 48 + r] = (r == 0) ? bf16bits(rel[n]) : (uint16_t)0;
  }
}

// ---------- fused rq + uncertainty GEMM: 32x32/wave, explicit reg double-buffer ----------
// 640 blocks (8x80 XCD-bijective), 4 waves/block; work = rowg(256 x 32rows) x cg(10 x 32cols).
// cg 0-7: unc cols cg*32; cg 8-9: rq cols (cg-8)*32 (W48b zero-padded; col48 -> 1.0).
__global__ void k_xw(const uint16_t* __restrict__ xb,
                     const uint16_t* __restrict__ w1b,
                     const uint16_t* __restrict__ W48b,
                     const float* __restrict__ b1,
                     const float* __restrict__ w2,
                     float* __restrict__ uncp,
                     uint16_t* __restrict__ rq_b) {
  int bid = blockIdx.x;
  int wid4 = (bid & 7) * 80 + (bid >> 3);            // XCD-contiguous
  int tid = threadIdx.x, wave = tid >> 6, lane = tid & 63;
  int w_id = wid4 * 4 + wave;
  int rowg = w_id / 10, cg = w_id - rowg * 10;
  int l15 = lane & 15, lg = lane >> 4;
  int row0 = rowg * 32;
  const uint16_t* wbase = (cg < 8) ? (w1b + (size_t)(cg * 32) * Hc)
                                   : (W48b + (size_t)((cg - 8) * 32) * Hc);
  const uint16_t* a0p = xb + (size_t)(row0 + l15) * Hc + lg * 8;
  const uint16_t* a1p = a0p + (size_t)16 * Hc;
  const uint16_t* b0p = wbase + (size_t)l15 * Hc + lg * 8;
  const uint16_t* b1p = b0p + (size_t)16 * Hc;
  f32x4 acc00 = {0.f,0.f,0.f,0.f}, acc01 = {0.f,0.f,0.f,0.f};
  f32x4 acc10 = {0.f,0.f,0.f,0.f}, acc11 = {0.f,0.f,0.f,0.f};
  bf16x8 a0c = *reinterpret_cast<const bf16x8*>(a0p);
  bf16x8 a1c = *reinterpret_cast<const bf16x8*>(a1p);
  bf16x8 b0c = *reinterpret_cast<const bf16x8*>(b0p);
  bf16x8 b1c = *reinterpret_cast<const bf16x8*>(b1p);
#pragma unroll
  for (int j = 0; j < 32; ++j) {
    bf16x8 a0n, a1n, b0n, b1n;
    if (j < 31) {                                   // issue next-step loads FIRST
      int kk = (j + 1) * 32;
      a0n = *reinterpret_cast<const bf16x8*>(a0p + kk);
      a1n = *reinterpret_cast<const bf16x8*>(a1p + kk);
      b0n = *reinterpret_cast<const bf16x8*>(b0p + kk);
      b1n = *reinterpret_cast<const bf16x8*>(b1p + kk);
    }
    acc00 = __builtin_amdgcn_mfma_f32_16x16x32_bf16(a0c, b0c, acc00, 0, 0, 0);
    acc01 = __builtin_amdgcn_mfma_f32_16x16x32_bf16(a0c, b1c, acc01, 0, 0, 0);
    acc10 = __builtin_amdgcn_mfma_f32_16x16x32_bf16(a1c, b0c, acc10, 0, 0, 0);
    acc11 = __builtin_amdgcn_mfma_f32_16x16x32_bf16(a1c, b1c, acc11, 0, 0, 0);
    if (j < 31) { a0c = a0n; a1c = a1n; b0c = b0n; b1c = b1n; }
  }
  if (cg < 8) {
    int c0 = cg * 32;
    float b1v0 = b1[c0 + l15],      w2v0 = w2[c0 + l15];
    float b1v1 = b1[c0 + 16 + l15], w2v1 = w2[c0 + 16 + l15];
    float part0[4], part1[4];
#pragma unroll
    for (int r = 0; r < 4; ++r) {
      float x00 = acc00[r] + b1v0, x01 = acc01[r] + b1v1;
      float x10 = acc10[r] + b1v0, x11 = acc11[r] + b1v1;
      float g00 = 0.5f * x00 * (1.f + erff(x00 * 0.70710678118654752f));
      float g01 = 0.5f * x01 * (1.f + erff(x01 * 0.70710678118654752f));
      float g10 = 0.5f * x10 * (1.f + erff(x10 * 0.70710678118654752f));
      float g11 = 0.5f * x11 * (1.f + erff(x11 * 0.70710678118654752f));
      part0[r] = fmaf(g00, w2v0, g01 * w2v1);
      part1[r] = fmaf(g10, w2v0, g11 * w2v1);
    }
#pragma unroll
    for (int d = 1; d < 16; d <<= 1)
#pragma unroll
      for (int r = 0; r < 4; ++r) {
        part0[r] += __shfl_xor(part0[r], d);
        part1[r] += __shfl_xor(part1[r], d);
      }
    if (l15 == 0) {
#pragma unroll
      for (int r = 0; r < 4; ++r) {
        uncp[(size_t)(row0 + lg * 4 + r) * 8 + cg] = part0[r];
        uncp[(size_t)(row0 + 16 + lg * 4 + r) * 8 + cg] = part1[r];
      }
    }
  } else {
    int c0 = (cg - 8) * 32;
    int colA = c0 + l15, colB = c0 + 16 + l15;
#pragma unroll
    for (int r = 0; r < 4; ++r) {
      uint16_t vA = bf16bits(acc00[r]);
      uint16_t vB = bf16bits(acc01[r]); if (colB == 48) vB = 0x3F80u;
      uint16_t uA = bf16bits(acc10[r]);
      uint16_t uB = bf16bits(acc11[r]); if (colB == 48) uB = 0x3F80u;
      rq_b[(size_t)(row0 + lg * 4 + r) * 64 + colA] = vA;
      rq_b[(size_t)(row0 + lg * 4 + r) * 64 + colB] = vB;
      rq_b[(size_t)(row0 + 16 + lg * 4 + r) * 64 + colA] = uA;
      rq_b[(size_t)(row0 + 16 + lg * 4 + r) * 64 + colB] = uB;
    }
  }
}

// ---------- scores via MFMA (swapped operands) + in-register top-8, reg-prefetch ----------
// blocks 0-1023: rowg = bid>>3 (64 q-rows), range = bid&7 (512 slots).
// block 1024: redsum of log_var -> stats.
__global__ __launch_bounds__(256) void k_scores_mfma(const uint16_t* __restrict__ rq_b,
                                                     const uint16_t* __restrict__ rk_b,
                                                     uint32_t* __restrict__ cand,
                                                     const float* __restrict__ log_var,
                                                     float* __restrict__ stats) {
  int tid = threadIdx.x;
  if (blockIdx.x == 1024) {                          // folded redsum
    float s = 0.f;
    for (int i = tid; i < ROWS; i += NT) s += log_var[i];
#pragma unroll
    for (int d = 32; d >= 1; d >>= 1) s += __shfl_down(s, d);
    __shared__ float ls[4];
    int lane = tid & 63, wid = tid >> 6;
    if (lane == 0) ls[wid] = s;
    __syncthreads();
    if (tid == 0) {
      s = ls[0] + ls[1] + ls[2] + ls[3];
      stats[0] = 1.f / (s * (1.f / ROWS) + 1e-6f);
    }
    return;
  }
  int wave = tid >> 6, lane = tid & 63;
  int l15 = lane & 15, lg = lane >> 4;
  int rowg = blockIdx.x >> 3, range = blockIdx.x & 7;
  int q0 = rowg * 64 + wave * 16;
  const uint16_t* qp = rq_b + (size_t)(q0 + l15) * 64 + lg * 8;
  bf16x8 qf1 = *reinterpret_cast<const bf16x8*>(qp);
  bf16x8 qf2 = *reinterpret_cast<const bf16x8*>(qp + 32);
  uint32_t top[8];
#pragma unroll
  for (int q = 0; q < 8; ++q) top[q] = 0u;
  int sbase = range * 512;
  const uint16_t* kp = rk_b + (size_t)(sbase + l15) * 64 + lg * 8;  // +t*16 slots = +t*1024
  bf16x8 a1c = *reinterpret_cast<const bf16x8*>(kp);
  bf16x8 a2c = *reinterpret_cast<const bf16x8*>(kp + 32);
  bf16x8 a3c = *reinterpret_cast<const bf16x8*>(kp + 1024);
  bf16x8 a4c = *reinterpret_cast<const bf16x8*>(kp + 1024 + 32);
#pragma unroll
  for (int t = 0; t < 32; t += 2) {
    bf16x8 a1n, a2n, a3n, a4n;
    if (t < 30) {                                    // prefetch next pair of tiles
      const uint16_t* kpn = kp + (size_t)(t + 2) * 1024;
      a1n = *reinterpret_cast<const bf16x8*>(kpn);
      a2n = *reinterpret_cast<const bf16x8*>(kpn + 32);
      a3n = *reinterpret_cast<const bf16x8*>(kpn + 1024);
      a4n = *reinterpret_cast<const bf16x8*>(kpn + 1024 + 32);
    }
    int s0 = sbase + t * 16;
    f32x4 acc0 = {0.f,0.f,0.f,0.f}, acc1 = {0.f,0.f,0.f,0.f};
    acc0 = __builtin_amdgcn_mfma_f32_16x16x32_bf16(a1c, qf1, acc0, 0, 0, 0);
    acc1 = __builtin_amdgcn_mfma_f32_16x16x32_bf16(a3c, qf1, acc1, 0, 0, 0);
    acc0 = __builtin_amdgcn_mfma_f32_16x16x32_bf16(a2c, qf2, acc0, 0, 0, 0);
    acc1 = __builtin_amdgcn_mfma_f32_16x16x32_bf16(a4c, qf2, acc1, 0, 0, 0);
#pragma unroll
    for (int r = 0; r < 4; ++r) top8_insert(top, pack_score(acc0[r], s0 + lg * 4 + r));
#pragma unroll
    for (int r = 0; r < 4; ++r) top8_insert(top, pack_score(acc1[r], s0 + 16 + lg * 4 + r));
    if (t < 30) { a1c = a1n; a2c = a2n; a3c = a3n; a4c = a4n; }
  }
#pragma unroll
  for (int dd = 16; dd <= 32; dd <<= 1) {
    uint32_t o[8];
#pragma unroll
    for (int q = 0; q < 8; ++q) o[q] = __shfl_xor(top[q], dd);
    merge_top8(top, o);
  }
  if (lg == 0) {
    int row = q0 + l15;
#pragma unroll
    for (int q = 0; q < 8; ++q) cand[((size_t)row * 8 + range) * 8 + q] = top[q];
  }
}

// ---------- merge ranges + softmax + gate + gather (bf16 table) + output ----------
__global__ __launch_bounds__(256) void k_final(const float* __restrict__ hidden,
                                               const uint16_t* __restrict__ avb,
                                               const uint32_t* __restrict__ cand,
                                               const float* __restrict__ log_var,
                                               const float* __restrict__ uncp,
                                               const float* __restrict__ stats,
                                               const float* __restrict__ b2,
                                               const float* __restrict__ gw,
                                               const float* __restrict__ gb,
                                               float* __restrict__ out) {
  int row = blockIdx.x;
  int tid = threadIdx.x;
  __shared__ float ws_[8]; __shared__ int wi_[8]; __shared__ float sgate;
  if (tid < 64) {
    int lane = tid;
    uint32_t l[8];
    float up = 0.f;
    if (lane < 8) {
      const uint32_t* c = cand + (size_t)row * 64 + lane * 8;
#pragma unroll
      for (int q = 0; q < 8; ++q) l[q] = c[q];
      up = uncp[(size_t)row * 8 + lane];
    } else {
#pragma unroll
      for (int q = 0; q < 8; ++q) l[q] = 0u;
    }
#pragma unroll
    for (int d = 1; d < 8; d <<= 1) {
      uint32_t o[8];
#pragma unroll
      for (int q = 0; q < 8; ++q) o[q] = __shfl_xor(l[q], d);
      merge_top8(l, o);
      up += __shfl_xor(up, d);
    }
    if (lane == 0) {
      float sc[8];
#pragma unroll
      for (int q = 0; q < 8; ++q) sc[q] = unpack_score(l[q]);
      float mx = sc[7];
      float e[8]; float sum = 0.f;
#pragma unroll
      for (int q = 0; q < 8; ++q) { e[q] = expf(sc[q] - mx); sum += e[q]; }
      float inv = 1.f / sum;
#pragma unroll
      for (int q = 0; q < 8; ++q) { ws_[q] = e[q] * inv; wi_[q] = (int)(l[q] & 0xFFFu); }
      float learned = up + b2[0];
      float nv = log_var[row] * stats[0];
      float sig = 1.f / (1.f + expf(-learned));
      float u = nv * 0.5f + sig * 2.5f;
      u = fminf(fmaxf(u, 0.f), 5.f);
      sgate = 1.f / (1.f + expf(-(gw[0] * u + gb[0])));
    }
  }
  __syncthreads();
  int h0 = tid * 4;
  float4 hv = *reinterpret_cast<const float4*>(hidden + (size_t)row * Hc + h0);
  float ax = 0.f, ay = 0.f, az = 0.f, aw = 0.f;
#pragma unroll
  for (int k = 0; k < 8; ++k) {
    float w = ws_[k];
    ushort4 v = *reinterpret_cast<const ushort4*>(avb + (size_t)wi_[k] * Hc + h0);
    ax = fmaf(w, bf2f(v.x), ax); ay = fmaf(w, bf2f(v.y), ay);
    az = fmaf(w, bf2f(v.z), az); aw = fmaf(w, bf2f(v.w), aw);
  }
  float g = sgate;
  float4 o;
  o.x = hv.x + g * ax; o.y = hv.y + g * ay; o.z = hv.z + g * az; o.w = hv.w + g * aw;
  *reinterpret_cast<float4*>(out + (size_t)row * Hc + h0) = o;
}

extern "C" void kernel_launch(void* const* d_in, const int* in_sizes, int n_in,
                              void* d_out, int out_size, void* d_ws, size_t ws_size,
                              hipStream_t stream) {
  const float* hidden     = (const float*)d_in[0];
  const float* q_proj_w   = (const float*)d_in[1];
  const float* router_w   = (const float*)d_in[2];
  const float* aux_keys   = (const float*)d_in[3];
  const float* aux_values = (const float*)d_in[4];
  const float* rel        = (const float*)d_in[5];
  const float* unc_w1     = (const float*)d_in[6];
  const float* unc_b1     = (const float*)d_in[7];
  const float* unc_w2     = (const float*)d_in[8];
  const float* unc_b2     = (const float*)d_in[9];
  const float* gate_w1    = (const float*)d_in[10];
  const float* gate_bias  = (const float*)d_in[11];
  float* out = (float*)d_out;

  uint8_t* w = (uint8_t*)d_ws;              // ~28.5 MB used
  uint16_t* xb    = (uint16_t*)w;                 w += (size_t)ROWS * Hc * 2;     // 16 MB
  uint16_t* w1b   = (uint16_t*)w;                 w += (size_t)256 * Hc * 2;      // 512 KB
  uint16_t* avb   = (uint16_t*)w;                 w += (size_t)Nc * Hc * 2;       // 8 MB
  uint16_t* W48b  = (uint16_t*)w;                 w += (size_t)64 * Hc * 2;       // 128 KB
  uint16_t* rq_b  = (uint16_t*)w;                 w += (size_t)ROWS * 64 * 2;     // 1 MB
  uint16_t* rk_b  = (uint16_t*)w;                 w += (size_t)Nc * 64 * 2;       // 512 KB
  float* log_var  = (float*)w;                    w += (size_t)ROWS * 4;
  float* uncp     = (float*)w;                    w += (size_t)ROWS * 8 * 4;      // 256 KB
  float* stats    = (float*)w;                    w += 256;
  uint32_t* cand  = (uint32_t*)w;                 w += (size_t)ROWS * 64 * 4;     // 2 MB

  k_prep_all<<<G_CVT + G_HB + G_W48 + G_RK, NT, 0, stream>>>(
      hidden, q_proj_w, router_w, aux_keys, aux_values, rel, unc_w1,
      xb, log_var, w1b, avb, W48b, rk_b);
  k_xw<<<640, NT, 0, stream>>>(xb, w1b, W48b, unc_b1, unc_w2, uncp, rq_b);
  k_scores_mfma<<<1025, NT, 0, stream>>>(rq_b, rk_b, cand, log_var, stats);
  k_final<<<ROWS, NT, 0, stream>>>(hidden, avb, cand, log_var, uncp,
                                   stats, unc_b2, gate_w1, gate_bias, out);
}

// Round 7
// 114.040 us; speedup vs baseline: 3.9825x; 1.2962x over previous
//
#include <hip/hip_runtime.h>
#include <hip/hip_bf16.h>
#include <math.h>
#include <stdint.h>

#define NT 256
constexpr int Hc = 1024, BOTc = 128, RDc = 48, Nc = 4096;
constexpr int ROWS = 8192;          // B*S
constexpr float INV_SQRT_RD = 0.14433756729740643f;  // 1/sqrt(48)

typedef short bf16x8 __attribute__((ext_vector_type(8)));
typedef float f32x4 __attribute__((ext_vector_type(4)));

// ---------- small helpers ----------
__device__ __forceinline__ uint32_t umin32(uint32_t a, uint32_t b) { return a < b ? a : b; }
__device__ __forceinline__ uint32_t umax32(uint32_t a, uint32_t b) { return a > b ? a : b; }
__device__ __forceinline__ void ce_asc(uint32_t& x, uint32_t& y) {
  uint32_t lo = umin32(x, y), hi = umax32(x, y); x = lo; y = hi;
}
__device__ __forceinline__ uint32_t pack_score(float s, int slot) {
  uint32_t u = __float_as_uint(s);
  u = (u & 0x80000000u) ? ~u : (u | 0x80000000u);
  return (u & 0xFFFFF000u) | (uint32_t)slot;
}
__device__ __forceinline__ float unpack_score(uint32_t p) {
  uint32_t m = p & 0xFFFFF000u;
  uint32_t f = (m & 0x80000000u) ? (m ^ 0x80000000u) : ~m;
  return __uint_as_float(f);
}
__device__ __forceinline__ void merge_top8(uint32_t a[8], const uint32_t b[8]) {
  uint32_t m[8];
#pragma unroll
  for (int i = 0; i < 8; ++i) m[i] = umax32(a[i], b[7 - i]);
  ce_asc(m[0], m[4]); ce_asc(m[1], m[5]); ce_asc(m[2], m[6]); ce_asc(m[3], m[7]);
  ce_asc(m[0], m[2]); ce_asc(m[1], m[3]); ce_asc(m[4], m[6]); ce_asc(m[5], m[7]);
  ce_asc(m[0], m[1]); ce_asc(m[2], m[3]); ce_asc(m[4], m[5]); ce_asc(m[6], m[7]);
#pragma unroll
  for (int i = 0; i < 8; ++i) a[i] = m[i];
}
__device__ __forceinline__ void top8_insert(uint32_t top[8], uint32_t p) {
  if (p > top[0]) {
    top[0] = p;
    ce_asc(top[0], top[1]); ce_asc(top[1], top[2]); ce_asc(top[2], top[3]);
    ce_asc(top[3], top[4]); ce_asc(top[4], top[5]); ce_asc(top[5], top[6]);
    ce_asc(top[6], top[7]);
  }
}
__device__ __forceinline__ uint16_t bf16bits(float x) {      // RNE
  uint32_t u = __float_as_uint(x);
  return (uint16_t)(((u + 0x7FFFu + ((u >> 16) & 1u)) >> 16) & 0xFFFFu);
}
__device__ __forceinline__ float bf2f(uint16_t h) {
  return __uint_as_float((uint32_t)h << 16);
}

// ---------- fused prep (grid-stride, deep MLP-free streaming) ----------
// sections: [0,2048) hb: 1 wave/row, 4 rows/block
//           [2048, 2592) cvt: w1->wcat rows 0-255, aux->avb, 8 float4/thread
//           [2592, 2656) w48 -> wcat rows 256-319 (rows 304+ zero)
//           [2656, 3424) rk
constexpr int GP_HB = 2048, GP_CVT = 544, GP_W48 = 64, GP_RK = 768;
__global__ __launch_bounds__(256) void k_prep_all(
    const float* __restrict__ hidden, const float* __restrict__ q_proj_w,
    const float* __restrict__ router_w, const float* __restrict__ aux_keys,
    const float* __restrict__ aux_values, const float* __restrict__ rel,
    const float* __restrict__ unc_w1,
    uint16_t* __restrict__ xb, float* __restrict__ log_var,
    uint16_t* __restrict__ wcat, uint16_t* __restrict__ avb,
    uint16_t* __restrict__ rk_b) {
  int bid = blockIdx.x;
  int tid = threadIdx.x;
  if (bid < GP_HB) {
    // hidden -> xb + per-row variance; one wave per row
    int wave = tid >> 6, lane = tid & 63;
    int row = bid * 4 + wave;
    const float4* hrow = reinterpret_cast<const float4*>(hidden + (size_t)row * Hc);
    float4 v[4];
#pragma unroll
    for (int i = 0; i < 4; ++i) v[i] = hrow[lane + 64 * i];
    float s = 0.f, q = 0.f;
#pragma unroll
    for (int i = 0; i < 4; ++i) {
      ushort4 h;
      h.x = bf16bits(v[i].x); h.y = bf16bits(v[i].y);
      h.z = bf16bits(v[i].z); h.w = bf16bits(v[i].w);
      *reinterpret_cast<ushort4*>(xb + (size_t)row * Hc + (lane + 64 * i) * 4) = h;
      s += v[i].x + v[i].y + v[i].z + v[i].w;
      q += v[i].x * v[i].x + v[i].y * v[i].y + v[i].z * v[i].z + v[i].w * v[i].w;
    }
#pragma unroll
    for (int d = 32; d >= 1; d >>= 1) { s += __shfl_down(s, d); q += __shfl_down(q, d); }
    if (lane == 0) {
      float mean = s * (1.f / Hc);
      float var = q * (1.f / Hc) - mean * mean;
      log_var[row] = log1pf(var);
    }
    return;
  }
  bid -= GP_HB;
  if (bid < GP_CVT) {
    // flat cvt: first 65536 f4 = unc_w1 -> wcat rows 0-255; rest = aux_values -> avb
    const int W1Q = 256 * Hc / 4;                    // 65536
#pragma unroll
    for (int i = 0; i < 8; ++i) {
      int idx = bid * 2048 + i * 256 + tid;
      float4 v; ushort4 h;
      if (idx < W1Q) {
        v = reinterpret_cast<const float4*>(unc_w1)[idx];
        h.x = bf16bits(v.x); h.y = bf16bits(v.y); h.z = bf16bits(v.z); h.w = bf16bits(v.w);
        reinterpret_cast<ushort4*>(wcat)[idx] = h;
      } else {
        int j = idx - W1Q;
        v = reinterpret_cast<const float4*>(aux_values)[j];
        h.x = bf16bits(v.x); h.y = bf16bits(v.y); h.z = bf16bits(v.z); h.w = bf16bits(v.w);
        reinterpret_cast<ushort4*>(avb)[j] = h;
      }
    }
    return;
  }
  bid -= GP_CVT;
  if (bid < GP_W48) {
    // wcat rows 256..319 = bf16(router_w @ q_proj_w), rows 304.. zero
    __shared__ float rw[BOTc];
    int j = bid;
    if (j >= RDc) {
      for (int hh = tid; hh < Hc; hh += NT) wcat[(size_t)(256 + j) * Hc + hh] = 0;
      return;
    }
    for (int d = tid; d < BOTc; d += NT) rw[d] = router_w[j * BOTc + d];
    __syncthreads();
    for (int hh = tid; hh < Hc; hh += NT) {
      float acc = 0.f;
#pragma unroll 8
      for (int d = 0; d < BOTc; ++d) acc = fmaf(rw[d], q_proj_w[d * Hc + hh], acc);
      wcat[(size_t)(256 + j) * Hc + hh] = bf16bits(acc);
    }
    return;
  }
  bid -= GP_W48;
  {
    // rk_b[n][64]
    int gid = bid * NT + tid;
    int n = gid / RDc, r = gid - n * RDc;
    float acc = 0.f;
#pragma unroll 8
    for (int d = 0; d < BOTc; ++d)
      acc = fmaf(aux_keys[n * BOTc + d], router_w[r * BOTc + d], acc);
    rk_b[(size_t)n * 64 + r] = bf16bits(acc * INV_SQRT_RD);
    if (r < 16) rk_b[(size_t)n * 64 + 48 + r] = (r == 0) ? bf16bits(rel[n]) : (uint16_t)0;
  }
}

// ---------- fused rq + uncertainty GEMM: LDS double-buffered 64x64x64 tiles ----------
// 640 blocks (8x80 XCD-bijective) = rowg(128 x 64rows) x colg(5 x 64cols of wcat).
// colg 0-3: unc cols; colg 4: rq (wcat rows 256-319, col48 -> 1.0).
// 4 waves: wave w -> output sub-tile (wr=w>>1)*32 rows, (wc=w&1)*32 cols.
__global__ __launch_bounds__(256) void k_xw(const uint16_t* __restrict__ xb,
                                            const uint16_t* __restrict__ wcat,
                                            const float* __restrict__ b1,
                                            const float* __restrict__ w2,
                                            float* __restrict__ uncp,
                                            uint16_t* __restrict__ rq_b) {
  __shared__ uint16_t As[2][64 * 72];                // +8-halves row pad: 2-way max conflicts
  __shared__ uint16_t Bs[2][64 * 72];
  int bid = blockIdx.x;
  int wid = (bid & 7) * 80 + (bid >> 3);             // XCD-contiguous (640 = 8*80)
  int rowg = wid / 5, colg = wid - rowg * 5;
  int tid = threadIdx.x, wave = tid >> 6, lane = tid & 63;
  int l15 = lane & 15, lg = lane >> 4;
  int wr = wave >> 1, wc = wave & 1;
  int row0 = rowg * 64, n0 = colg * 64;
  // staging map: thread -> (srow, 16B seg); chunk2 = srow+32
  int srow = tid >> 3, sseg = tid & 7;
  const uint16_t* agp = xb + (size_t)(row0 + srow) * Hc + sseg * 8;
  const uint16_t* bgp = wcat + (size_t)(n0 + srow) * Hc + sseg * 8;
  int sboff = srow * 72 + sseg * 8;
  int arow = wr * 32 + l15, brow = wc * 32 + l15;

  bf16x8 ra0 = *reinterpret_cast<const bf16x8*>(agp);
  bf16x8 ra1 = *reinterpret_cast<const bf16x8*>(agp + (size_t)32 * Hc);
  bf16x8 rb0 = *reinterpret_cast<const bf16x8*>(bgp);
  bf16x8 rb1 = *reinterpret_cast<const bf16x8*>(bgp + (size_t)32 * Hc);
  f32x4 acc00 = {0.f,0.f,0.f,0.f}, acc01 = {0.f,0.f,0.f,0.f};
  f32x4 acc10 = {0.f,0.f,0.f,0.f}, acc11 = {0.f,0.f,0.f,0.f};

  for (int t = 0; t < 16; ++t) {
    int buf = t & 1;
    *reinterpret_cast<bf16x8*>(&As[buf][sboff]) = ra0;
    *reinterpret_cast<bf16x8*>(&As[buf][sboff + 32 * 72]) = ra1;
    *reinterpret_cast<bf16x8*>(&Bs[buf][sboff]) = rb0;
    *reinterpret_cast<bf16x8*>(&Bs[buf][sboff + 32 * 72]) = rb1;
    if (t < 15) {                                    // issue next-tile loads now;
      int k0 = (t + 1) * 64;                         // vmcnt wait lands at next ds_write
      ra0 = *reinterpret_cast<const bf16x8*>(agp + k0);
      ra1 = *reinterpret_cast<const bf16x8*>(agp + (size_t)32 * Hc + k0);
      rb0 = *reinterpret_cast<const bf16x8*>(bgp + k0);
      rb1 = *reinterpret_cast<const bf16x8*>(bgp + (size_t)32 * Hc + k0);
    }
    __syncthreads();
#pragma unroll
    for (int ks = 0; ks < 2; ++ks) {
      bf16x8 a0 = *reinterpret_cast<const bf16x8*>(&As[buf][arow * 72 + ks * 32 + lg * 8]);
      bf16x8 a1 = *reinterpret_cast<const bf16x8*>(&As[buf][(arow + 16) * 72 + ks * 32 + lg * 8]);
      bf16x8 b0 = *reinterpret_cast<const bf16x8*>(&Bs[buf][brow * 72 + ks * 32 + lg * 8]);
      bf16x8 b1f = *reinterpret_cast<const bf16x8*>(&Bs[buf][(brow + 16) * 72 + ks * 32 + lg * 8]);
      acc00 = __builtin_amdgcn_mfma_f32_16x16x32_bf16(a0, b0, acc00, 0, 0, 0);
      acc01 = __builtin_amdgcn_mfma_f32_16x16x32_bf16(a0, b1f, acc01, 0, 0, 0);
      acc10 = __builtin_amdgcn_mfma_f32_16x16x32_bf16(a1, b0, acc10, 0, 0, 0);
      acc11 = __builtin_amdgcn_mfma_f32_16x16x32_bf16(a1, b1f, acc11, 0, 0, 0);
    }
    __syncthreads();
  }
  if (colg < 4) {
    int gc0 = n0 + wc * 32 + l15;                    // cols gc0, gc0+16
    float b1v0 = b1[gc0],      w2v0 = w2[gc0];
    float b1v1 = b1[gc0 + 16], w2v1 = w2[gc0 + 16];
    int strip = colg * 2 + wc;
    float part0[4], part1[4];
#pragma unroll
    for (int r = 0; r < 4; ++r) {
      float x00 = acc00[r] + b1v0, x01 = acc01[r] + b1v1;
      float x10 = acc10[r] + b1v0, x11 = acc11[r] + b1v1;
      float g00 = 0.5f * x00 * (1.f + erff(x00 * 0.70710678118654752f));
      float g01 = 0.5f * x01 * (1.f + erff(x01 * 0.70710678118654752f));
      float g10 = 0.5f * x10 * (1.f + erff(x10 * 0.70710678118654752f));
      float g11 = 0.5f * x11 * (1.f + erff(x11 * 0.70710678118654752f));
      part0[r] = fmaf(g00, w2v0, g01 * w2v1);
      part1[r] = fmaf(g10, w2v0, g11 * w2v1);
    }
#pragma unroll
    for (int d = 1; d < 16; d <<= 1)
#pragma unroll
      for (int r = 0; r < 4; ++r) {
        part0[r] += __shfl_xor(part0[r], d);
        part1[r] += __shfl_xor(part1[r], d);
      }
    if (l15 == 0) {
#pragma unroll
      for (int r = 0; r < 4; ++r) {
        uncp[(size_t)(row0 + wr * 32 + lg * 4 + r) * 8 + strip] = part0[r];
        uncp[(size_t)(row0 + wr * 32 + 16 + lg * 4 + r) * 8 + strip] = part1[r];
      }
    }
  } else {
    int colA = wc * 32 + l15, colB = colA + 16;      // rq cols 0..63
#pragma unroll
    for (int r = 0; r < 4; ++r) {
      int rA = row0 + wr * 32 + lg * 4 + r, rB = rA + 16;
      uint16_t vA = bf16bits(acc00[r]);
      uint16_t vB = (colB == 48) ? (uint16_t)0x3F80u : bf16bits(acc01[r]);
      uint16_t uA = bf16bits(acc10[r]);
      uint16_t uB = (colB == 48) ? (uint16_t)0x3F80u : bf16bits(acc11[r]);
      rq_b[(size_t)rA * 64 + colA] = vA;
      rq_b[(size_t)rA * 64 + colB] = vB;
      rq_b[(size_t)rB * 64 + colA] = uA;
      rq_b[(size_t)rB * 64 + colB] = uB;
    }
  }
}

// ---------- scores via MFMA (swapped operands) + in-register top-8, reg-prefetch ----------
// blocks 0-1023: rowg = bid>>3 (64 q-rows), range = bid&7 (512 slots).
// block 1024: redsum of log_var -> stats.
__global__ __launch_bounds__(256) void k_scores_mfma(const uint16_t* __restrict__ rq_b,
                                                     const uint16_t* __restrict__ rk_b,
                                                     uint32_t* __restrict__ cand,
                                                     const float* __restrict__ log_var,
                                                     float* __restrict__ stats) {
  int tid = threadIdx.x;
  if (blockIdx.x == 1024) {                          // folded redsum
    float s = 0.f;
    for (int i = tid; i < ROWS; i += NT) s += log_var[i];
#pragma unroll
    for (int d = 32; d >= 1; d >>= 1) s += __shfl_down(s, d);
    __shared__ float ls[4];
    int lane = tid & 63, wid = tid >> 6;
    if (lane == 0) ls[wid] = s;
    __syncthreads();
    if (tid == 0) {
      s = ls[0] + ls[1] + ls[2] + ls[3];
      stats[0] = 1.f / (s * (1.f / ROWS) + 1e-6f);
    }
    return;
  }
  int wave = tid >> 6, lane = tid & 63;
  int l15 = lane & 15, lg = lane >> 4;
  int rowg = blockIdx.x >> 3, range = blockIdx.x & 7;
  int q0 = rowg * 64 + wave * 16;
  const uint16_t* qp = rq_b + (size_t)(q0 + l15) * 64 + lg * 8;
  bf16x8 qf1 = *reinterpret_cast<const bf16x8*>(qp);
  bf16x8 qf2 = *reinterpret_cast<const bf16x8*>(qp + 32);
  uint32_t top[8];
#pragma unroll
  for (int q = 0; q < 8; ++q) top[q] = 0u;
  int sbase = range * 512;
  const uint16_t* kp = rk_b + (size_t)(sbase + l15) * 64 + lg * 8;
  bf16x8 a1c = *reinterpret_cast<const bf16x8*>(kp);
  bf16x8 a2c = *reinterpret_cast<const bf16x8*>(kp + 32);
  bf16x8 a3c = *reinterpret_cast<const bf16x8*>(kp + 1024);
  bf16x8 a4c = *reinterpret_cast<const bf16x8*>(kp + 1024 + 32);
#pragma unroll
  for (int t = 0; t < 32; t += 2) {
    bf16x8 a1n, a2n, a3n, a4n;
    if (t < 30) {
      const uint16_t* kpn = kp + (size_t)(t + 2) * 1024;
      a1n = *reinterpret_cast<const bf16x8*>(kpn);
      a2n = *reinterpret_cast<const bf16x8*>(kpn + 32);
      a3n = *reinterpret_cast<const bf16x8*>(kpn + 1024);
      a4n = *reinterpret_cast<const bf16x8*>(kpn + 1024 + 32);
    }
    int s0 = sbase + t * 16;
    f32x4 acc0 = {0.f,0.f,0.f,0.f}, acc1 = {0.f,0.f,0.f,0.f};
    acc0 = __builtin_amdgcn_mfma_f32_16x16x32_bf16(a1c, qf1, acc0, 0, 0, 0);
    acc1 = __builtin_amdgcn_mfma_f32_16x16x32_bf16(a3c, qf1, acc1, 0, 0, 0);
    acc0 = __builtin_amdgcn_mfma_f32_16x16x32_bf16(a2c, qf2, acc0, 0, 0, 0);
    acc1 = __builtin_amdgcn_mfma_f32_16x16x32_bf16(a4c, qf2, acc1, 0, 0, 0);
#pragma unroll
    for (int r = 0; r < 4; ++r) top8_insert(top, pack_score(acc0[r], s0 + lg * 4 + r));
#pragma unroll
    for (int r = 0; r < 4; ++r) top8_insert(top, pack_score(acc1[r], s0 + 16 + lg * 4 + r));
    if (t < 30) { a1c = a1n; a2c = a2n; a3c = a3n; a4c = a4n; }
  }
#pragma unroll
  for (int dd = 16; dd <= 32; dd <<= 1) {
    uint32_t o[8];
#pragma unroll
    for (int q = 0; q < 8; ++q) o[q] = __shfl_xor(top[q], dd);
    merge_top8(top, o);
  }
  if (lg == 0) {
    int row = q0 + l15;
#pragma unroll
    for (int q = 0; q < 8; ++q) cand[((size_t)row * 8 + range) * 8 + q] = top[q];
  }
}

// ---------- merge ranges + softmax + gate + gather (bf16 table) + output ----------
__global__ __launch_bounds__(256) void k_final(const float* __restrict__ hidden,
                                               const uint16_t* __restrict__ avb,
                                               const uint32_t* __restrict__ cand,
                                               const float* __restrict__ log_var,
                                               const float* __restrict__ uncp,
                                               const float* __restrict__ stats,
                                               const float* __restrict__ b2,
                                               const float* __restrict__ gw,
                                               const float* __restrict__ gb,
                                               float* __restrict__ out) {
  int row = blockIdx.x;
  int tid = threadIdx.x;
  __shared__ float ws_[8]; __shared__ int wi_[8]; __shared__ float sgate;
  if (tid < 64) {
    int lane = tid;
    uint32_t l[8];
    float up = 0.f;
    if (lane < 8) {
      const uint32_t* c = cand + (size_t)row * 64 + lane * 8;
#pragma unroll
      for (int q = 0; q < 8; ++q) l[q] = c[q];
      up = uncp[(size_t)row * 8 + lane];
    } else {
#pragma unroll
      for (int q = 0; q < 8; ++q) l[q] = 0u;
    }
#pragma unroll
    for (int d = 1; d < 8; d <<= 1) {
      uint32_t o[8];
#pragma unroll
      for (int q = 0; q < 8; ++q) o[q] = __shfl_xor(l[q], d);
      merge_top8(l, o);
      up += __shfl_xor(up, d);
    }
    if (lane == 0) {
      float sc[8];
#pragma unroll
      for (int q = 0; q < 8; ++q) sc[q] = unpack_score(l[q]);
      float mx = sc[7];
      float e[8]; float sum = 0.f;
#pragma unroll
      for (int q = 0; q < 8; ++q) { e[q] = expf(sc[q] - mx); sum += e[q]; }
      float inv = 1.f / sum;
#pragma unroll
      for (int q = 0; q < 8; ++q) { ws_[q] = e[q] * inv; wi_[q] = (int)(l[q] & 0xFFFu); }
      float learned = up + b2[0];
      float nv = log_var[row] * stats[0];
      float sig = 1.f / (1.f + expf(-learned));
      float u = nv * 0.5f + sig * 2.5f;
      u = fminf(fmaxf(u, 0.f), 5.f);
      sgate = 1.f / (1.f + expf(-(gw[0] * u + gb[0])));
    }
  }
  __syncthreads();
  int h0 = tid * 4;
  float4 hv = *reinterpret_cast<const float4*>(hidden + (size_t)row * Hc + h0);
  float ax = 0.f, ay = 0.f, az = 0.f, aw = 0.f;
#pragma unroll
  for (int k = 0; k < 8; ++k) {
    float w = ws_[k];
    ushort4 v = *reinterpret_cast<const ushort4*>(avb + (size_t)wi_[k] * Hc + h0);
    ax = fmaf(w, bf2f(v.x), ax); ay = fmaf(w, bf2f(v.y), ay);
    az = fmaf(w, bf2f(v.z), az); aw = fmaf(w, bf2f(v.w), aw);
  }
  float g = sgate;
  float4 o;
  o.x = hv.x + g * ax; o.y = hv.y + g * ay; o.z = hv.z + g * az; o.w = hv.w + g * aw;
  *reinterpret_cast<float4*>(out + (size_t)row * Hc + h0) = o;
}

extern "C" void kernel_launch(void* const* d_in, const int* in_sizes, int n_in,
                              void* d_out, int out_size, void* d_ws, size_t ws_size,
                              hipStream_t stream) {
  const float* hidden     = (const float*)d_in[0];
  const float* q_proj_w   = (const float*)d_in[1];
  const float* router_w   = (const float*)d_in[2];
  const float* aux_keys   = (const float*)d_in[3];
  const float* aux_values = (const float*)d_in[4];
  const float* rel        = (const float*)d_in[5];
  const float* unc_w1     = (const float*)d_in[6];
  const float* unc_b1     = (const float*)d_in[7];
  const float* unc_w2     = (const float*)d_in[8];
  const float* unc_b2     = (const float*)d_in[9];
  const float* gate_w1    = (const float*)d_in[10];
  const float* gate_bias  = (const float*)d_in[11];
  float* out = (float*)d_out;

  uint8_t* w = (uint8_t*)d_ws;              // ~28.5 MB used
  uint16_t* xb    = (uint16_t*)w;                 w += (size_t)ROWS * Hc * 2;     // 16 MB
  uint16_t* wcat  = (uint16_t*)w;                 w += (size_t)320 * Hc * 2;      // 640 KB
  uint16_t* avb   = (uint16_t*)w;                 w += (size_t)Nc * Hc * 2;       // 8 MB
  uint16_t* rq_b  = (uint16_t*)w;                 w += (size_t)ROWS * 64 * 2;     // 1 MB
  uint16_t* rk_b  = (uint16_t*)w;                 w += (size_t)Nc * 64 * 2;       // 512 KB
  float* log_var  = (float*)w;                    w += (size_t)ROWS * 4;
  float* uncp     = (float*)w;                    w += (size_t)ROWS * 8 * 4;      // 256 KB
  float* stats    = (float*)w;                    w += 256;
  uint32_t* cand  = (uint32_t*)w;                 w += (size_t)ROWS * 64 * 4;     // 2 MB

  k_prep_all<<<GP_HB + GP_CVT + GP_W48 + GP_RK, NT, 0, stream>>>(
      hidden, q_proj_w, router_w, aux_keys, aux_values, rel, unc_w1,
      xb, log_var, wcat, avb, rk_b);
  k_xw<<<640, NT, 0, stream>>>(xb, wcat, unc_b1, unc_w2, uncp, rq_b);
  k_scores_mfma<<<1025, NT, 0, stream>>>(rq_b, rk_b, cand, log_var, stats);
  k_final<<<ROWS, NT, 0, stream>>>(hidden, avb, cand, log_var, uncp,
                                   stats, unc_b2, gate_w1, gate_bias, out);
}

// Round 8
// 98.615 us; speedup vs baseline: 4.6055x; 1.1564x over previous
//
#include <hip/hip_runtime.h>
#include <hip/hip_bf16.h>
#include <math.h>
#include <stdint.h>

#define NT 256
constexpr int Hc = 1024, BOTc = 128, RDc = 48, Nc = 4096;
constexpr int ROWS = 8192;          // B*S
constexpr float INV_SQRT_RD = 0.14433756729740643f;  // 1/sqrt(48)

typedef short bf16x8 __attribute__((ext_vector_type(8)));
typedef float f32x4 __attribute__((ext_vector_type(4)));

// ---------- small helpers ----------
__device__ __forceinline__ uint32_t umin32(uint32_t a, uint32_t b) { return a < b ? a : b; }
__device__ __forceinline__ uint32_t umax32(uint32_t a, uint32_t b) { return a > b ? a : b; }
__device__ __forceinline__ void ce_asc(uint32_t& x, uint32_t& y) {
  uint32_t lo = umin32(x, y), hi = umax32(x, y); x = lo; y = hi;
}
__device__ __forceinline__ uint32_t pack_score(float s, int slot) {
  uint32_t u = __float_as_uint(s);
  u = (u & 0x80000000u) ? ~u : (u | 0x80000000u);
  return (u & 0xFFFFF000u) | (uint32_t)slot;
}
__device__ __forceinline__ float unpack_score(uint32_t p) {
  uint32_t m = p & 0xFFFFF000u;
  uint32_t f = (m & 0x80000000u) ? (m ^ 0x80000000u) : ~m;
  return __uint_as_float(f);
}
__device__ __forceinline__ void merge_top8(uint32_t a[8], const uint32_t b[8]) {
  uint32_t m[8];
#pragma unroll
  for (int i = 0; i < 8; ++i) m[i] = umax32(a[i], b[7 - i]);
  ce_asc(m[0], m[4]); ce_asc(m[1], m[5]); ce_asc(m[2], m[6]); ce_asc(m[3], m[7]);
  ce_asc(m[0], m[2]); ce_asc(m[1], m[3]); ce_asc(m[4], m[6]); ce_asc(m[5], m[7]);
  ce_asc(m[0], m[1]); ce_asc(m[2], m[3]); ce_asc(m[4], m[5]); ce_asc(m[6], m[7]);
#pragma unroll
  for (int i = 0; i < 8; ++i) a[i] = m[i];
}
__device__ __forceinline__ void top8_insert(uint32_t top[8], uint32_t p) {
  if (p > top[0]) {
    top[0] = p;
    ce_asc(top[0], top[1]); ce_asc(top[1], top[2]); ce_asc(top[2], top[3]);
    ce_asc(top[3], top[4]); ce_asc(top[4], top[5]); ce_asc(top[5], top[6]);
    ce_asc(top[6], top[7]);
  }
}
__device__ __forceinline__ uint16_t bf16bits(float x) {      // RNE
  uint32_t u = __float_as_uint(x);
  return (uint16_t)(((u + 0x7FFFu + ((u >> 16) & 1u)) >> 16) & 0xFFFFu);
}
__device__ __forceinline__ float bf2f(uint16_t h) {
  return __uint_as_float((uint32_t)h << 16);
}

// ---------- fused prep; latency-bound sections FIRST, then BW flood ----------
// [0,64)       w48 -> wcat rows 256-319 (rows 304+ zero), 16 loads in flight
// [64,832)     rk
// [832,1856)   hb: 2 rows/wave, 8 loads up-front
// [1856,1888)  cvt w1 -> wcat rows 0-255 (branch-free)
// [1888,2400)  cvt aux -> avb (branch-free)
constexpr int GP_W48 = 64, GP_RK = 768, GP_HB = 1024, GP_CVW = 32, GP_CVA = 512;
__global__ __launch_bounds__(256) void k_prep_all(
    const float* __restrict__ hidden, const float* __restrict__ q_proj_w,
    const float* __restrict__ router_w, const float* __restrict__ aux_keys,
    const float* __restrict__ aux_values, const float* __restrict__ rel,
    const float* __restrict__ unc_w1,
    uint16_t* __restrict__ xb, float* __restrict__ log_var,
    uint16_t* __restrict__ wcat, uint16_t* __restrict__ avb,
    uint16_t* __restrict__ rk_b) {
  int bid = blockIdx.x;
  int tid = threadIdx.x;
  if (bid < GP_W48) {
    // wcat rows 256..319 = bf16(router_w @ q_proj_w); rows 304+ zero
    __shared__ float rw[BOTc];
    int j = bid;
    if (j >= RDc) {
      for (int hh = tid; hh < Hc; hh += NT) wcat[(size_t)(256 + j) * Hc + hh] = 0;
      return;
    }
    for (int d = tid; d < BOTc; d += NT) rw[d] = router_w[j * BOTc + d];
    __syncthreads();
    float acc[4] = {0.f, 0.f, 0.f, 0.f};
#pragma unroll 4
    for (int d = 0; d < BOTc; ++d) {
      float r = rw[d];
#pragma unroll
      for (int jj = 0; jj < 4; ++jj)
        acc[jj] = fmaf(r, q_proj_w[d * Hc + tid + 256 * jj], acc[jj]);
    }
#pragma unroll
    for (int jj = 0; jj < 4; ++jj)
      wcat[(size_t)(256 + j) * Hc + tid + 256 * jj] = bf16bits(acc[jj]);
    return;
  }
  bid -= GP_W48;
  if (bid < GP_RK) {
    // rk_b[n][64]
    int gid = bid * NT + tid;
    int n = gid / RDc, r = gid - n * RDc;
    float acc = 0.f;
#pragma unroll 8
    for (int d = 0; d < BOTc; ++d)
      acc = fmaf(aux_keys[n * BOTc + d], router_w[r * BOTc + d], acc);
    rk_b[(size_t)n * 64 + r] = bf16bits(acc * INV_SQRT_RD);
    if (r < 16) rk_b[(size_t)n * 64 + 48 + r] = (r == 0) ? bf16bits(rel[n]) : (uint16_t)0;
    return;
  }
  bid -= GP_RK;
  if (bid < GP_HB) {
    // hidden -> xb + variance; 2 rows per wave, 8 loads issued up-front
    int wave = tid >> 6, lane = tid & 63;
    int row = bid * 8 + wave * 2;
    const float4* r0 = reinterpret_cast<const float4*>(hidden + (size_t)row * Hc);
    const float4* r1 = reinterpret_cast<const float4*>(hidden + (size_t)(row + 1) * Hc);
    float4 v0[4], v1[4];
#pragma unroll
    for (int i = 0; i < 4; ++i) v0[i] = r0[lane + 64 * i];
#pragma unroll
    for (int i = 0; i < 4; ++i) v1[i] = r1[lane + 64 * i];
    float s0 = 0.f, q0 = 0.f, s1 = 0.f, q1 = 0.f;
#pragma unroll
    for (int i = 0; i < 4; ++i) {
      ushort4 h;
      h.x = bf16bits(v0[i].x); h.y = bf16bits(v0[i].y);
      h.z = bf16bits(v0[i].z); h.w = bf16bits(v0[i].w);
      *reinterpret_cast<ushort4*>(xb + (size_t)row * Hc + (lane + 64 * i) * 4) = h;
      s0 += v0[i].x + v0[i].y + v0[i].z + v0[i].w;
      q0 += v0[i].x * v0[i].x + v0[i].y * v0[i].y + v0[i].z * v0[i].z + v0[i].w * v0[i].w;
    }
#pragma unroll
    for (int i = 0; i < 4; ++i) {
      ushort4 h;
      h.x = bf16bits(v1[i].x); h.y = bf16bits(v1[i].y);
      h.z = bf16bits(v1[i].z); h.w = bf16bits(v1[i].w);
      *reinterpret_cast<ushort4*>(xb + (size_t)(row + 1) * Hc + (lane + 64 * i) * 4) = h;
      s1 += v1[i].x + v1[i].y + v1[i].z + v1[i].w;
      q1 += v1[i].x * v1[i].x + v1[i].y * v1[i].y + v1[i].z * v1[i].z + v1[i].w * v1[i].w;
    }
#pragma unroll
    for (int d = 32; d >= 1; d >>= 1) {
      s0 += __shfl_down(s0, d); q0 += __shfl_down(q0, d);
      s1 += __shfl_down(s1, d); q1 += __shfl_down(q1, d);
    }
    if (lane == 0) {
      float m0 = s0 * (1.f / Hc), m1 = s1 * (1.f / Hc);
      log_var[row]     = log1pf(q0 * (1.f / Hc) - m0 * m0);
      log_var[row + 1] = log1pf(q1 * (1.f / Hc) - m1 * m1);
    }
    return;
  }
  bid -= GP_HB;
  if (bid < GP_CVW) {
    // unc_w1 -> wcat rows 0-255; 8 f4/thread, branch-free
    float4 v[8];
    int base = bid * 2048 + tid;
#pragma unroll
    for (int i = 0; i < 8; ++i) v[i] = reinterpret_cast<const float4*>(unc_w1)[base + i * 256];
#pragma unroll
    for (int i = 0; i < 8; ++i) {
      ushort4 h;
      h.x = bf16bits(v[i].x); h.y = bf16bits(v[i].y);
      h.z = bf16bits(v[i].z); h.w = bf16bits(v[i].w);
      reinterpret_cast<ushort4*>(wcat)[base + i * 256] = h;
    }
    return;
  }
  bid -= GP_CVW;
  {
    // aux_values -> avb; 8 f4/thread, branch-free
    float4 v[8];
    int base = bid * 2048 + tid;
#pragma unroll
    for (int i = 0; i < 8; ++i) v[i] = reinterpret_cast<const float4*>(aux_values)[base + i * 256];
#pragma unroll
    for (int i = 0; i < 8; ++i) {
      ushort4 h;
      h.x = bf16bits(v[i].x); h.y = bf16bits(v[i].y);
      h.z = bf16bits(v[i].z); h.w = bf16bits(v[i].w);
      reinterpret_cast<ushort4*>(avb)[base + i * 256] = h;
    }
  }
}

// ---------- fused rq + uncertainty GEMM: LDS double-buffered 64x64x64 tiles ----------
// 640 blocks (8x80 XCD-bijective) = rowg(128 x 64rows) x colg(5 x 64cols of wcat).
// colg 0-3: unc cols; colg 4: rq (wcat rows 256-319, col48 -> 1.0).
__global__ __launch_bounds__(256) void k_xw(const uint16_t* __restrict__ xb,
                                            const uint16_t* __restrict__ wcat,
                                            const float* __restrict__ b1,
                                            const float* __restrict__ w2,
                                            float* __restrict__ uncp,
                                            uint16_t* __restrict__ rq_b) {
  __shared__ uint16_t As[2][64 * 72];                // +8-halves row pad: 2-way max conflicts
  __shared__ uint16_t Bs[2][64 * 72];
  int bid = blockIdx.x;
  int wid = (bid & 7) * 80 + (bid >> 3);             // XCD-contiguous (640 = 8*80)
  int rowg = wid / 5, colg = wid - rowg * 5;
  int tid = threadIdx.x, wave = tid >> 6, lane = tid & 63;
  int l15 = lane & 15, lg = lane >> 4;
  int wr = wave >> 1, wc = wave & 1;
  int row0 = rowg * 64, n0 = colg * 64;
  int srow = tid >> 3, sseg = tid & 7;
  const uint16_t* agp = xb + (size_t)(row0 + srow) * Hc + sseg * 8;
  const uint16_t* bgp = wcat + (size_t)(n0 + srow) * Hc + sseg * 8;
  int sboff = srow * 72 + sseg * 8;
  int arow = wr * 32 + l15, brow = wc * 32 + l15;

  bf16x8 ra0 = *reinterpret_cast<const bf16x8*>(agp);
  bf16x8 ra1 = *reinterpret_cast<const bf16x8*>(agp + (size_t)32 * Hc);
  bf16x8 rb0 = *reinterpret_cast<const bf16x8*>(bgp);
  bf16x8 rb1 = *reinterpret_cast<const bf16x8*>(bgp + (size_t)32 * Hc);
  f32x4 acc00 = {0.f,0.f,0.f,0.f}, acc01 = {0.f,0.f,0.f,0.f};
  f32x4 acc10 = {0.f,0.f,0.f,0.f}, acc11 = {0.f,0.f,0.f,0.f};

  for (int t = 0; t < 16; ++t) {
    int buf = t & 1;
    *reinterpret_cast<bf16x8*>(&As[buf][sboff]) = ra0;
    *reinterpret_cast<bf16x8*>(&As[buf][sboff + 32 * 72]) = ra1;
    *reinterpret_cast<bf16x8*>(&Bs[buf][sboff]) = rb0;
    *reinterpret_cast<bf16x8*>(&Bs[buf][sboff + 32 * 72]) = rb1;
    if (t < 15) {                                    // issue next-tile loads now
      int k0 = (t + 1) * 64;
      ra0 = *reinterpret_cast<const bf16x8*>(agp + k0);
      ra1 = *reinterpret_cast<const bf16x8*>(agp + (size_t)32 * Hc + k0);
      rb0 = *reinterpret_cast<const bf16x8*>(bgp + k0);
      rb1 = *reinterpret_cast<const bf16x8*>(bgp + (size_t)32 * Hc + k0);
    }
    __syncthreads();
#pragma unroll
    for (int ks = 0; ks < 2; ++ks) {
      bf16x8 a0 = *reinterpret_cast<const bf16x8*>(&As[buf][arow * 72 + ks * 32 + lg * 8]);
      bf16x8 a1 = *reinterpret_cast<const bf16x8*>(&As[buf][(arow + 16) * 72 + ks * 32 + lg * 8]);
      bf16x8 b0 = *reinterpret_cast<const bf16x8*>(&Bs[buf][brow * 72 + ks * 32 + lg * 8]);
      bf16x8 b1f = *reinterpret_cast<const bf16x8*>(&Bs[buf][(brow + 16) * 72 + ks * 32 + lg * 8]);
      acc00 = __builtin_amdgcn_mfma_f32_16x16x32_bf16(a0, b0, acc00, 0, 0, 0);
      acc01 = __builtin_amdgcn_mfma_f32_16x16x32_bf16(a0, b1f, acc01, 0, 0, 0);
      acc10 = __builtin_amdgcn_mfma_f32_16x16x32_bf16(a1, b0, acc10, 0, 0, 0);
      acc11 = __builtin_amdgcn_mfma_f32_16x16x32_bf16(a1, b1f, acc11, 0, 0, 0);
    }
    __syncthreads();
  }
  if (colg < 4) {
    int gc0 = n0 + wc * 32 + l15;
    float b1v0 = b1[gc0],      w2v0 = w2[gc0];
    float b1v1 = b1[gc0 + 16], w2v1 = w2[gc0 + 16];
    int strip = colg * 2 + wc;
    float part0[4], part1[4];
#pragma unroll
    for (int r = 0; r < 4; ++r) {
      float x00 = acc00[r] + b1v0, x01 = acc01[r] + b1v1;
      float x10 = acc10[r] + b1v0, x11 = acc11[r] + b1v1;
      float g00 = 0.5f * x00 * (1.f + erff(x00 * 0.70710678118654752f));
      float g01 = 0.5f * x01 * (1.f + erff(x01 * 0.70710678118654752f));
      float g10 = 0.5f * x10 * (1.f + erff(x10 * 0.70710678118654752f));
      float g11 = 0.5f * x11 * (1.f + erff(x11 * 0.70710678118654752f));
      part0[r] = fmaf(g00, w2v0, g01 * w2v1);
      part1[r] = fmaf(g10, w2v0, g11 * w2v1);
    }
#pragma unroll
    for (int d = 1; d < 16; d <<= 1)
#pragma unroll
      for (int r = 0; r < 4; ++r) {
        part0[r] += __shfl_xor(part0[r], d);
        part1[r] += __shfl_xor(part1[r], d);
      }
    if (l15 == 0) {
#pragma unroll
      for (int r = 0; r < 4; ++r) {
        uncp[(size_t)(row0 + wr * 32 + lg * 4 + r) * 8 + strip] = part0[r];
        uncp[(size_t)(row0 + wr * 32 + 16 + lg * 4 + r) * 8 + strip] = part1[r];
      }
    }
  } else {
    int colA = wc * 32 + l15, colB = colA + 16;
#pragma unroll
    for (int r = 0; r < 4; ++r) {
      int rA = row0 + wr * 32 + lg * 4 + r, rB = rA + 16;
      uint16_t vA = bf16bits(acc00[r]);
      uint16_t vB = (colB == 48) ? (uint16_t)0x3F80u : bf16bits(acc01[r]);
      uint16_t uA = bf16bits(acc10[r]);
      uint16_t uB = (colB == 48) ? (uint16_t)0x3F80u : bf16bits(acc11[r]);
      rq_b[(size_t)rA * 64 + colA] = vA;
      rq_b[(size_t)rA * 64 + colB] = vB;
      rq_b[(size_t)rB * 64 + colA] = uA;
      rq_b[(size_t)rB * 64 + colB] = uB;
    }
  }
}

// ---------- scores via MFMA (swapped operands) + in-register top-8, reg-prefetch ----------
__global__ __launch_bounds__(256) void k_scores_mfma(const uint16_t* __restrict__ rq_b,
                                                     const uint16_t* __restrict__ rk_b,
                                                     uint32_t* __restrict__ cand,
                                                     const float* __restrict__ log_var,
                                                     float* __restrict__ stats) {
  int tid = threadIdx.x;
  if (blockIdx.x == 1024) {                          // folded redsum
    float s = 0.f;
    for (int i = tid; i < ROWS; i += NT) s += log_var[i];
#pragma unroll
    for (int d = 32; d >= 1; d >>= 1) s += __shfl_down(s, d);
    __shared__ float ls[4];
    int lane = tid & 63, wid = tid >> 6;
    if (lane == 0) ls[wid] = s;
    __syncthreads();
    if (tid == 0) {
      s = ls[0] + ls[1] + ls[2] + ls[3];
      stats[0] = 1.f / (s * (1.f / ROWS) + 1e-6f);
    }
    return;
  }
  int wave = tid >> 6, lane = tid & 63;
  int l15 = lane & 15, lg = lane >> 4;
  int rowg = blockIdx.x >> 3, range = blockIdx.x & 7;
  int q0 = rowg * 64 + wave * 16;
  const uint16_t* qp = rq_b + (size_t)(q0 + l15) * 64 + lg * 8;
  bf16x8 qf1 = *reinterpret_cast<const bf16x8*>(qp);
  bf16x8 qf2 = *reinterpret_cast<const bf16x8*>(qp + 32);
  uint32_t top[8];
#pragma unroll
  for (int q = 0; q < 8; ++q) top[q] = 0u;
  int sbase = range * 512;
  const uint16_t* kp = rk_b + (size_t)(sbase + l15) * 64 + lg * 8;
  bf16x8 a1c = *reinterpret_cast<const bf16x8*>(kp);
  bf16x8 a2c = *reinterpret_cast<const bf16x8*>(kp + 32);
  bf16x8 a3c = *reinterpret_cast<const bf16x8*>(kp + 1024);
  bf16x8 a4c = *reinterpret_cast<const bf16x8*>(kp + 1024 + 32);
#pragma unroll
  for (int t = 0; t < 32; t += 2) {
    bf16x8 a1n, a2n, a3n, a4n;
    if (t < 30) {
      const uint16_t* kpn = kp + (size_t)(t + 2) * 1024;
      a1n = *reinterpret_cast<const bf16x8*>(kpn);
      a2n = *reinterpret_cast<const bf16x8*>(kpn + 32);
      a3n = *reinterpret_cast<const bf16x8*>(kpn + 1024);
      a4n = *reinterpret_cast<const bf16x8*>(kpn + 1024 + 32);
    }
    int s0 = sbase + t * 16;
    f32x4 acc0 = {0.f,0.f,0.f,0.f}, acc1 = {0.f,0.f,0.f,0.f};
    acc0 = __builtin_amdgcn_mfma_f32_16x16x32_bf16(a1c, qf1, acc0, 0, 0, 0);
    acc1 = __builtin_amdgcn_mfma_f32_16x16x32_bf16(a3c, qf1, acc1, 0, 0, 0);
    acc0 = __builtin_amdgcn_mfma_f32_16x16x32_bf16(a2c, qf2, acc0, 0, 0, 0);
    acc1 = __builtin_amdgcn_mfma_f32_16x16x32_bf16(a4c, qf2, acc1, 0, 0, 0);
#pragma unroll
    for (int r = 0; r < 4; ++r) top8_insert(top, pack_score(acc0[r], s0 + lg * 4 + r));
#pragma unroll
    for (int r = 0; r < 4; ++r) top8_insert(top, pack_score(acc1[r], s0 + 16 + lg * 4 + r));
    if (t < 30) { a1c = a1n; a2c = a2n; a3c = a3n; a4c = a4n; }
  }
#pragma unroll
  for (int dd = 16; dd <= 32; dd <<= 1) {
    uint32_t o[8];
#pragma unroll
    for (int q = 0; q < 8; ++q) o[q] = __shfl_xor(top[q], dd);
    merge_top8(top, o);
  }
  if (lg == 0) {
    int row = q0 + l15;
#pragma unroll
    for (int q = 0; q < 8; ++q) cand[((size_t)row * 8 + range) * 8 + q] = top[q];
  }
}

// ---------- merge ranges + softmax + gate + gather (bf16) + output (residual from xb) ----------
__global__ __launch_bounds__(256) void k_final(const uint16_t* __restrict__ xb,
                                               const uint16_t* __restrict__ avb,
                                               const uint32_t* __restrict__ cand,
                                               const float* __restrict__ log_var,
                                               const float* __restrict__ uncp,
                                               const float* __restrict__ stats,
                                               const float* __restrict__ b2,
                                               const float* __restrict__ gw,
                                               const float* __restrict__ gb,
                                               float* __restrict__ out) {
  int row = blockIdx.x;
  int tid = threadIdx.x;
  __shared__ float ws_[8]; __shared__ int wi_[8]; __shared__ float sgate;
  if (tid < 64) {
    int lane = tid;
    uint32_t l[8];
    float up = 0.f;
    if (lane < 8) {
      const uint32_t* c = cand + (size_t)row * 64 + lane * 8;
#pragma unroll
      for (int q = 0; q < 8; ++q) l[q] = c[q];
      up = uncp[(size_t)row * 8 + lane];
    } else {
#pragma unroll
      for (int q = 0; q < 8; ++q) l[q] = 0u;
    }
#pragma unroll
    for (int d = 1; d < 8; d <<= 1) {
      uint32_t o[8];
#pragma unroll
      for (int q = 0; q < 8; ++q) o[q] = __shfl_xor(l[q], d);
      merge_top8(l, o);
      up += __shfl_xor(up, d);
    }
    if (lane == 0) {
      float sc[8];
#pragma unroll
      for (int q = 0; q < 8; ++q) sc[q] = unpack_score(l[q]);
      float mx = sc[7];
      float e[8]; float sum = 0.f;
#pragma unroll
      for (int q = 0; q < 8; ++q) { e[q] = expf(sc[q] - mx); sum += e[q]; }
      float inv = 1.f / sum;
#pragma unroll
      for (int q = 0; q < 8; ++q) { ws_[q] = e[q] * inv; wi_[q] = (int)(l[q] & 0xFFFu); }
      float learned = up + b2[0];
      float nv = log_var[row] * stats[0];
      float sig = 1.f / (1.f + expf(-learned));
      float u = nv * 0.5f + sig * 2.5f;
      u = fminf(fmaxf(u, 0.f), 5.f);
      sgate = 1.f / (1.f + expf(-(gw[0] * u + gb[0])));
    }
  }
  __syncthreads();
  int h0 = tid * 4;
  ushort4 hb = *reinterpret_cast<const ushort4*>(xb + (size_t)row * Hc + h0);
  float ax = 0.f, ay = 0.f, az = 0.f, aw = 0.f;
#pragma unroll
  for (int k = 0; k < 8; ++k) {
    float w = ws_[k];
    ushort4 v = *reinterpret_cast<const ushort4*>(avb + (size_t)wi_[k] * Hc + h0);
    ax = fmaf(w, bf2f(v.x), ax); ay = fmaf(w, bf2f(v.y), ay);
    az = fmaf(w, bf2f(v.z), az); aw = fmaf(w, bf2f(v.w), aw);
  }
  float g = sgate;
  float4 o;
  o.x = bf2f(hb.x) + g * ax; o.y = bf2f(hb.y) + g * ay;
  o.z = bf2f(hb.z) + g * az; o.w = bf2f(hb.w) + g * aw;
  *reinterpret_cast<float4*>(out + (size_t)row * Hc + h0) = o;
}

extern "C" void kernel_launch(void* const* d_in, const int* in_sizes, int n_in,
                              void* d_out, int out_size, void* d_ws, size_t ws_size,
                              hipStream_t stream) {
  const float* hidden     = (const float*)d_in[0];
  const float* q_proj_w   = (const float*)d_in[1];
  const float* router_w   = (const float*)d_in[2];
  const float* aux_keys   = (const float*)d_in[3];
  const float* aux_values = (const float*)d_in[4];
  const float* rel        = (const float*)d_in[5];
  const float* unc_w1     = (const float*)d_in[6];
  const float* unc_b1     = (const float*)d_in[7];
  const float* unc_w2     = (const float*)d_in[8];
  const float* unc_b2     = (const float*)d_in[9];
  const float* gate_w1    = (const float*)d_in[10];
  const float* gate_bias  = (const float*)d_in[11];
  float* out = (float*)d_out;

  uint8_t* w = (uint8_t*)d_ws;              // ~28.5 MB used
  uint16_t* xb    = (uint16_t*)w;                 w += (size_t)ROWS * Hc * 2;     // 16 MB
  uint16_t* wcat  = (uint16_t*)w;                 w += (size_t)320 * Hc * 2;      // 640 KB
  uint16_t* avb   = (uint16_t*)w;                 w += (size_t)Nc * Hc * 2;       // 8 MB
  uint16_t* rq_b  = (uint16_t*)w;                 w += (size_t)ROWS * 64 * 2;     // 1 MB
  uint16_t* rk_b  = (uint16_t*)w;                 w += (size_t)Nc * 64 * 2;       // 512 KB
  float* log_var  = (float*)w;                    w += (size_t)ROWS * 4;
  float* uncp     = (float*)w;                    w += (size_t)ROWS * 8 * 4;      // 256 KB
  float* stats    = (float*)w;                    w += 256;
  uint32_t* cand  = (uint32_t*)w;                 w += (size_t)ROWS * 64 * 4;     // 2 MB

  k_prep_all<<<GP_W48 + GP_RK + GP_HB + GP_CVW + GP_CVA, NT, 0, stream>>>(
      hidden, q_proj_w, router_w, aux_keys, aux_values, rel, unc_w1,
      xb, log_var, wcat, avb, rk_b);
  k_xw<<<640, NT, 0, stream>>>(xb, wcat, unc_b1, unc_w2, uncp, rq_b);
  k_scores_mfma<<<1025, NT, 0, stream>>>(rq_b, rk_b, cand, log_var, stats);
  k_final<<<ROWS, NT, 0, stream>>>(xb, avb, cand, log_var, uncp,
                                   stats, unc_b2, gate_w1, gate_bias, out);
}

// Round 9
// 93.660 us; speedup vs baseline: 4.8491x; 1.0529x over previous
//
#include <hip/hip_runtime.h>
#include <hip/hip_bf16.h>
#include <math.h>
#include <stdint.h>

#define NT 256
constexpr int Hc = 1024, BOTc = 128, RDc = 48, Nc = 4096;
constexpr int ROWS = 8192;          // B*S
constexpr float INV_SQRT_RD = 0.14433756729740643f;  // 1/sqrt(48)

typedef short bf16x8 __attribute__((ext_vector_type(8)));
typedef float f32x4 __attribute__((ext_vector_type(4)));

// ---------- small helpers ----------
__device__ __forceinline__ uint32_t umin32(uint32_t a, uint32_t b) { return a < b ? a : b; }
__device__ __forceinline__ uint32_t umax32(uint32_t a, uint32_t b) { return a > b ? a : b; }
__device__ __forceinline__ void ce_asc(uint32_t& x, uint32_t& y) {
  uint32_t lo = umin32(x, y), hi = umax32(x, y); x = lo; y = hi;
}
__device__ __forceinline__ uint32_t pack_score(float s, int slot) {
  uint32_t u = __float_as_uint(s);
  u = (u & 0x80000000u) ? ~u : (u | 0x80000000u);
  return (u & 0xFFFFF000u) | (uint32_t)slot;
}
__device__ __forceinline__ float unpack_score(uint32_t p) {
  uint32_t m = p & 0xFFFFF000u;
  uint32_t f = (m & 0x80000000u) ? (m ^ 0x80000000u) : ~m;
  return __uint_as_float(f);
}
__device__ __forceinline__ void merge_top8(uint32_t a[8], const uint32_t b[8]) {
  uint32_t m[8];
#pragma unroll
  for (int i = 0; i < 8; ++i) m[i] = umax32(a[i], b[7 - i]);
  ce_asc(m[0], m[4]); ce_asc(m[1], m[5]); ce_asc(m[2], m[6]); ce_asc(m[3], m[7]);
  ce_asc(m[0], m[2]); ce_asc(m[1], m[3]); ce_asc(m[4], m[6]); ce_asc(m[5], m[7]);
  ce_asc(m[0], m[1]); ce_asc(m[2], m[3]); ce_asc(m[4], m[5]); ce_asc(m[6], m[7]);
#pragma unroll
  for (int i = 0; i < 8; ++i) a[i] = m[i];
}
__device__ __forceinline__ void top8_insert(uint32_t top[8], uint32_t p) {
  if (p > top[0]) {
    top[0] = p;
    ce_asc(top[0], top[1]); ce_asc(top[1], top[2]); ce_asc(top[2], top[3]);
    ce_asc(top[3], top[4]); ce_asc(top[4], top[5]); ce_asc(top[5], top[6]);
    ce_asc(top[6], top[7]);
  }
}
__device__ __forceinline__ uint16_t bf16bits(float x) {      // RNE
  uint32_t u = __float_as_uint(x);
  return (uint16_t)(((u + 0x7FFFu + ((u >> 16) & 1u)) >> 16) & 0xFFFFu);
}
__device__ __forceinline__ float bf2f(uint16_t h) {
  return __uint_as_float((uint32_t)h << 16);
}

// ---------- fused prep; latency-bound sections FIRST, then BW flood ----------
constexpr int GP_W48 = 64, GP_RK = 768, GP_HB = 1024, GP_CVW = 32, GP_CVA = 512;
__global__ __launch_bounds__(256) void k_prep_all(
    const float* __restrict__ hidden, const float* __restrict__ q_proj_w,
    const float* __restrict__ router_w, const float* __restrict__ aux_keys,
    const float* __restrict__ aux_values, const float* __restrict__ rel,
    const float* __restrict__ unc_w1,
    uint16_t* __restrict__ xb, float* __restrict__ log_var,
    uint16_t* __restrict__ wcat, uint16_t* __restrict__ avb,
    uint16_t* __restrict__ rk_b) {
  int bid = blockIdx.x;
  int tid = threadIdx.x;
  if (bid < GP_W48) {
    __shared__ float rw[BOTc];
    int j = bid;
    if (j >= RDc) {
      for (int hh = tid; hh < Hc; hh += NT) wcat[(size_t)(256 + j) * Hc + hh] = 0;
      return;
    }
    for (int d = tid; d < BOTc; d += NT) rw[d] = router_w[j * BOTc + d];
    __syncthreads();
    float acc[4] = {0.f, 0.f, 0.f, 0.f};
#pragma unroll 4
    for (int d = 0; d < BOTc; ++d) {
      float r = rw[d];
#pragma unroll
      for (int jj = 0; jj < 4; ++jj)
        acc[jj] = fmaf(r, q_proj_w[d * Hc + tid + 256 * jj], acc[jj]);
    }
#pragma unroll
    for (int jj = 0; jj < 4; ++jj)
      wcat[(size_t)(256 + j) * Hc + tid + 256 * jj] = bf16bits(acc[jj]);
    return;
  }
  bid -= GP_W48;
  if (bid < GP_RK) {
    int gid = bid * NT + tid;
    int n = gid / RDc, r = gid - n * RDc;
    float acc = 0.f;
#pragma unroll 8
    for (int d = 0; d < BOTc; ++d)
      acc = fmaf(aux_keys[n * BOTc + d], router_w[r * BOTc + d], acc);
    rk_b[(size_t)n * 64 + r] = bf16bits(acc * INV_SQRT_RD);
    if (r < 16) rk_b[(size_t)n * 64 + 48 + r] = (r == 0) ? bf16bits(rel[n]) : (uint16_t)0;
    return;
  }
  bid -= GP_RK;
  if (bid < GP_HB) {
    int wave = tid >> 6, lane = tid & 63;
    int row = bid * 8 + wave * 2;
    const float4* r0 = reinterpret_cast<const float4*>(hidden + (size_t)row * Hc);
    const float4* r1 = reinterpret_cast<const float4*>(hidden + (size_t)(row + 1) * Hc);
    float4 v0[4], v1[4];
#pragma unroll
    for (int i = 0; i < 4; ++i) v0[i] = r0[lane + 64 * i];
#pragma unroll
    for (int i = 0; i < 4; ++i) v1[i] = r1[lane + 64 * i];
    float s0 = 0.f, q0 = 0.f, s1 = 0.f, q1 = 0.f;
#pragma unroll
    for (int i = 0; i < 4; ++i) {
      ushort4 h;
      h.x = bf16bits(v0[i].x); h.y = bf16bits(v0[i].y);
      h.z = bf16bits(v0[i].z); h.w = bf16bits(v0[i].w);
      *reinterpret_cast<ushort4*>(xb + (size_t)row * Hc + (lane + 64 * i) * 4) = h;
      s0 += v0[i].x + v0[i].y + v0[i].z + v0[i].w;
      q0 += v0[i].x * v0[i].x + v0[i].y * v0[i].y + v0[i].z * v0[i].z + v0[i].w * v0[i].w;
    }
#pragma unroll
    for (int i = 0; i < 4; ++i) {
      ushort4 h;
      h.x = bf16bits(v1[i].x); h.y = bf16bits(v1[i].y);
      h.z = bf16bits(v1[i].z); h.w = bf16bits(v1[i].w);
      *reinterpret_cast<ushort4*>(xb + (size_t)(row + 1) * Hc + (lane + 64 * i) * 4) = h;
      s1 += v1[i].x + v1[i].y + v1[i].z + v1[i].w;
      q1 += v1[i].x * v1[i].x + v1[i].y * v1[i].y + v1[i].z * v1[i].z + v1[i].w * v1[i].w;
    }
#pragma unroll
    for (int d = 32; d >= 1; d >>= 1) {
      s0 += __shfl_down(s0, d); q0 += __shfl_down(q0, d);
      s1 += __shfl_down(s1, d); q1 += __shfl_down(q1, d);
    }
    if (lane == 0) {
      float m0 = s0 * (1.f / Hc), m1 = s1 * (1.f / Hc);
      log_var[row]     = log1pf(q0 * (1.f / Hc) - m0 * m0);
      log_var[row + 1] = log1pf(q1 * (1.f / Hc) - m1 * m1);
    }
    return;
  }
  bid -= GP_HB;
  if (bid < GP_CVW) {
    float4 v[8];
    int base = bid * 2048 + tid;
#pragma unroll
    for (int i = 0; i < 8; ++i) v[i] = reinterpret_cast<const float4*>(unc_w1)[base + i * 256];
#pragma unroll
    for (int i = 0; i < 8; ++i) {
      ushort4 h;
      h.x = bf16bits(v[i].x); h.y = bf16bits(v[i].y);
      h.z = bf16bits(v[i].z); h.w = bf16bits(v[i].w);
      reinterpret_cast<ushort4*>(wcat)[base + i * 256] = h;
    }
    return;
  }
  bid -= GP_CVW;
  {
    float4 v[8];
    int base = bid * 2048 + tid;
#pragma unroll
    for (int i = 0; i < 8; ++i) v[i] = reinterpret_cast<const float4*>(aux_values)[base + i * 256];
#pragma unroll
    for (int i = 0; i < 8; ++i) {
      ushort4 h;
      h.x = bf16bits(v[i].x); h.y = bf16bits(v[i].y);
      h.z = bf16bits(v[i].z); h.w = bf16bits(v[i].w);
      reinterpret_cast<ushort4*>(avb)[base + i * 256] = h;
    }
  }
}

// ---------- fused rq + uncertainty GEMM: LDS dbuf, prefetch-distance 2, 1 barrier/step ----------
// blocks 0-639 (8x80 XCD-bijective) = rowg(128 x 64rows) x colg(5 x 64cols of wcat).
// colg 0-3: unc cols; colg 4: rq (wcat rows 256-319, col48 -> 1.0). block 640: redsum.
__global__ __launch_bounds__(256) void k_xw(const uint16_t* __restrict__ xb,
                                            const uint16_t* __restrict__ wcat,
                                            const float* __restrict__ b1,
                                            const float* __restrict__ w2,
                                            const float* __restrict__ log_var,
                                            float* __restrict__ stats,
                                            float* __restrict__ uncp,
                                            uint16_t* __restrict__ rq_b) {
  int bid = blockIdx.x;
  int tid = threadIdx.x;
  if (bid == 640) {                                  // folded redsum (log_var from prep)
    float s = 0.f;
    for (int i = tid; i < ROWS; i += NT) s += log_var[i];
#pragma unroll
    for (int d = 32; d >= 1; d >>= 1) s += __shfl_down(s, d);
    __shared__ float ls[4];
    int lane = tid & 63, wv = tid >> 6;
    if (lane == 0) ls[wv] = s;
    __syncthreads();
    if (tid == 0) {
      s = ls[0] + ls[1] + ls[2] + ls[3];
      stats[0] = 1.f / (s * (1.f / ROWS) + 1e-6f);
    }
    return;
  }
  __shared__ uint16_t As[2][64 * 72];
  __shared__ uint16_t Bs[2][64 * 72];
  int wid = (bid & 7) * 80 + (bid >> 3);             // XCD-contiguous (640 = 8*80)
  int rowg = wid / 5, colg = wid - rowg * 5;
  int wave = tid >> 6, lane = tid & 63;
  int l15 = lane & 15, lg = lane >> 4;
  int wr = wave >> 1, wc = wave & 1;
  int row0 = rowg * 64, n0 = colg * 64;
  int srow = tid >> 3, sseg = tid & 7;
  const uint16_t* agp = xb + (size_t)(row0 + srow) * Hc + sseg * 8;
  const uint16_t* bgp = wcat + (size_t)(n0 + srow) * Hc + sseg * 8;
  int sboff = srow * 72 + sseg * 8;
  int arow = wr * 32 + l15, brow = wc * 32 + l15;

  // stage A = even tiles, stage B = odd tiles (prefetch distance 2)
  bf16x8 a0A = *reinterpret_cast<const bf16x8*>(agp);
  bf16x8 a1A = *reinterpret_cast<const bf16x8*>(agp + (size_t)32 * Hc);
  bf16x8 b0A = *reinterpret_cast<const bf16x8*>(bgp);
  bf16x8 b1A = *reinterpret_cast<const bf16x8*>(bgp + (size_t)32 * Hc);
  bf16x8 a0B = *reinterpret_cast<const bf16x8*>(agp + 64);
  bf16x8 a1B = *reinterpret_cast<const bf16x8*>(agp + (size_t)32 * Hc + 64);
  bf16x8 b0B = *reinterpret_cast<const bf16x8*>(bgp + 64);
  bf16x8 b1B = *reinterpret_cast<const bf16x8*>(bgp + (size_t)32 * Hc + 64);
  f32x4 acc00 = {0.f,0.f,0.f,0.f}, acc01 = {0.f,0.f,0.f,0.f};
  f32x4 acc10 = {0.f,0.f,0.f,0.f}, acc11 = {0.f,0.f,0.f,0.f};

  for (int tt = 0; tt < 16; tt += 2) {
    // even step: buf 0, stage A
    *reinterpret_cast<bf16x8*>(&As[0][sboff]) = a0A;
    *reinterpret_cast<bf16x8*>(&As[0][sboff + 32 * 72]) = a1A;
    *reinterpret_cast<bf16x8*>(&Bs[0][sboff]) = b0A;
    *reinterpret_cast<bf16x8*>(&Bs[0][sboff + 32 * 72]) = b1A;
    if (tt + 2 < 16) {
      int k0 = (tt + 2) * 64;
      a0A = *reinterpret_cast<const bf16x8*>(agp + k0);
      a1A = *reinterpret_cast<const bf16x8*>(agp + (size_t)32 * Hc + k0);
      b0A = *reinterpret_cast<const bf16x8*>(bgp + k0);
      b1A = *reinterpret_cast<const bf16x8*>(bgp + (size_t)32 * Hc + k0);
    }
    __syncthreads();
#pragma unroll
    for (int ks = 0; ks < 2; ++ks) {
      bf16x8 a0 = *reinterpret_cast<const bf16x8*>(&As[0][arow * 72 + ks * 32 + lg * 8]);
      bf16x8 a1 = *reinterpret_cast<const bf16x8*>(&As[0][(arow + 16) * 72 + ks * 32 + lg * 8]);
      bf16x8 b0 = *reinterpret_cast<const bf16x8*>(&Bs[0][brow * 72 + ks * 32 + lg * 8]);
      bf16x8 b1f = *reinterpret_cast<const bf16x8*>(&Bs[0][(brow + 16) * 72 + ks * 32 + lg * 8]);
      acc00 = __builtin_amdgcn_mfma_f32_16x16x32_bf16(a0, b0, acc00, 0, 0, 0);
      acc01 = __builtin_amdgcn_mfma_f32_16x16x32_bf16(a0, b1f, acc01, 0, 0, 0);
      acc10 = __builtin_amdgcn_mfma_f32_16x16x32_bf16(a1, b0, acc10, 0, 0, 0);
      acc11 = __builtin_amdgcn_mfma_f32_16x16x32_bf16(a1, b1f, acc11, 0, 0, 0);
    }
    // odd step: buf 1, stage B (write-after-read safe: buf1's last readers
    // were separated by the barrier above)
    *reinterpret_cast<bf16x8*>(&As[1][sboff]) = a0B;
    *reinterpret_cast<bf16x8*>(&As[1][sboff + 32 * 72]) = a1B;
    *reinterpret_cast<bf16x8*>(&Bs[1][sboff]) = b0B;
    *reinterpret_cast<bf16x8*>(&Bs[1][sboff + 32 * 72]) = b1B;
    if (tt + 3 < 16) {
      int k0 = (tt + 3) * 64;
      a0B = *reinterpret_cast<const bf16x8*>(agp + k0);
      a1B = *reinterpret_cast<const bf16x8*>(agp + (size_t)32 * Hc + k0);
      b0B = *reinterpret_cast<const bf16x8*>(bgp + k0);
      b1B = *reinterpret_cast<const bf16x8*>(bgp + (size_t)32 * Hc + k0);
    }
    __syncthreads();
#pragma unroll
    for (int ks = 0; ks < 2; ++ks) {
      bf16x8 a0 = *reinterpret_cast<const bf16x8*>(&As[1][arow * 72 + ks * 32 + lg * 8]);
      bf16x8 a1 = *reinterpret_cast<const bf16x8*>(&As[1][(arow + 16) * 72 + ks * 32 + lg * 8]);
      bf16x8 b0 = *reinterpret_cast<const bf16x8*>(&Bs[1][brow * 72 + ks * 32 + lg * 8]);
      bf16x8 b1f = *reinterpret_cast<const bf16x8*>(&Bs[1][(brow + 16) * 72 + ks * 32 + lg * 8]);
      acc00 = __builtin_amdgcn_mfma_f32_16x16x32_bf16(a0, b0, acc00, 0, 0, 0);
      acc01 = __builtin_amdgcn_mfma_f32_16x16x32_bf16(a0, b1f, acc01, 0, 0, 0);
      acc10 = __builtin_amdgcn_mfma_f32_16x16x32_bf16(a1, b0, acc10, 0, 0, 0);
      acc11 = __builtin_amdgcn_mfma_f32_16x16x32_bf16(a1, b1f, acc11, 0, 0, 0);
    }
  }
  if (colg < 4) {
    int gc0 = n0 + wc * 32 + l15;
    float b1v0 = b1[gc0],      w2v0 = w2[gc0];
    float b1v1 = b1[gc0 + 16], w2v1 = w2[gc0 + 16];
    int strip = colg * 2 + wc;
    float part0[4], part1[4];
#pragma unroll
    for (int r = 0; r < 4; ++r) {
      float x00 = acc00[r] + b1v0, x01 = acc01[r] + b1v1;
      float x10 = acc10[r] + b1v0, x11 = acc11[r] + b1v1;
      float g00 = 0.5f * x00 * (1.f + erff(x00 * 0.70710678118654752f));
      float g01 = 0.5f * x01 * (1.f + erff(x01 * 0.70710678118654752f));
      float g10 = 0.5f * x10 * (1.f + erff(x10 * 0.70710678118654752f));
      float g11 = 0.5f * x11 * (1.f + erff(x11 * 0.70710678118654752f));
      part0[r] = fmaf(g00, w2v0, g01 * w2v1);
      part1[r] = fmaf(g10, w2v0, g11 * w2v1);
    }
#pragma unroll
    for (int d = 1; d < 16; d <<= 1)
#pragma unroll
      for (int r = 0; r < 4; ++r) {
        part0[r] += __shfl_xor(part0[r], d);
        part1[r] += __shfl_xor(part1[r], d);
      }
    if (l15 == 0) {
#pragma unroll
      for (int r = 0; r < 4; ++r) {
        uncp[(size_t)(row0 + wr * 32 + lg * 4 + r) * 8 + strip] = part0[r];
        uncp[(size_t)(row0 + wr * 32 + 16 + lg * 4 + r) * 8 + strip] = part1[r];
      }
    }
  } else {
    int colA = wc * 32 + l15, colB = colA + 16;
#pragma unroll
    for (int r = 0; r < 4; ++r) {
      int rA = row0 + wr * 32 + lg * 4 + r, rB = rA + 16;
      uint16_t vA = bf16bits(acc00[r]);
      uint16_t vB = (colB == 48) ? (uint16_t)0x3F80u : bf16bits(acc01[r]);
      uint16_t uA = bf16bits(acc10[r]);
      uint16_t uB = (colB == 48) ? (uint16_t)0x3F80u : bf16bits(acc11[r]);
      rq_b[(size_t)rA * 64 + colA] = vA;
      rq_b[(size_t)rA * 64 + colB] = vB;
      rq_b[(size_t)rB * 64 + colA] = uA;
      rq_b[(size_t)rB * 64 + colB] = uB;
    }
  }
}

// ---------- scores via MFMA (swapped operands) + in-register top-8, reg-prefetch ----------
__global__ __launch_bounds__(256) void k_scores_mfma(const uint16_t* __restrict__ rq_b,
                                                     const uint16_t* __restrict__ rk_b,
                                                     uint32_t* __restrict__ cand) {
  int tid = threadIdx.x;
  int wave = tid >> 6, lane = tid & 63;
  int l15 = lane & 15, lg = lane >> 4;
  int rowg = blockIdx.x >> 3, range = blockIdx.x & 7;
  int q0 = rowg * 64 + wave * 16;
  const uint16_t* qp = rq_b + (size_t)(q0 + l15) * 64 + lg * 8;
  bf16x8 qf1 = *reinterpret_cast<const bf16x8*>(qp);
  bf16x8 qf2 = *reinterpret_cast<const bf16x8*>(qp + 32);
  uint32_t top[8];
#pragma unroll
  for (int q = 0; q < 8; ++q) top[q] = 0u;
  int sbase = range * 512;
  const uint16_t* kp = rk_b + (size_t)(sbase + l15) * 64 + lg * 8;
  bf16x8 a1c = *reinterpret_cast<const bf16x8*>(kp);
  bf16x8 a2c = *reinterpret_cast<const bf16x8*>(kp + 32);
  bf16x8 a3c = *reinterpret_cast<const bf16x8*>(kp + 1024);
  bf16x8 a4c = *reinterpret_cast<const bf16x8*>(kp + 1024 + 32);
#pragma unroll
  for (int t = 0; t < 32; t += 2) {
    bf16x8 a1n, a2n, a3n, a4n;
    if (t < 30) {
      const uint16_t* kpn = kp + (size_t)(t + 2) * 1024;
      a1n = *reinterpret_cast<const bf16x8*>(kpn);
      a2n = *reinterpret_cast<const bf16x8*>(kpn + 32);
      a3n = *reinterpret_cast<const bf16x8*>(kpn + 1024);
      a4n = *reinterpret_cast<const bf16x8*>(kpn + 1024 + 32);
    }
    int s0 = sbase + t * 16;
    f32x4 acc0 = {0.f,0.f,0.f,0.f}, acc1 = {0.f,0.f,0.f,0.f};
    acc0 = __builtin_amdgcn_mfma_f32_16x16x32_bf16(a1c, qf1, acc0, 0, 0, 0);
    acc1 = __builtin_amdgcn_mfma_f32_16x16x32_bf16(a3c, qf1, acc1, 0, 0, 0);
    acc0 = __builtin_amdgcn_mfma_f32_16x16x32_bf16(a2c, qf2, acc0, 0, 0, 0);
    acc1 = __builtin_amdgcn_mfma_f32_16x16x32_bf16(a4c, qf2, acc1, 0, 0, 0);
#pragma unroll
    for (int r = 0; r < 4; ++r) top8_insert(top, pack_score(acc0[r], s0 + lg * 4 + r));
#pragma unroll
    for (int r = 0; r < 4; ++r) top8_insert(top, pack_score(acc1[r], s0 + 16 + lg * 4 + r));
    if (t < 30) { a1c = a1n; a2c = a2n; a3c = a3n; a4c = a4n; }
  }
#pragma unroll
  for (int dd = 16; dd <= 32; dd <<= 1) {
    uint32_t o[8];
#pragma unroll
    for (int q = 0; q < 8; ++q) o[q] = __shfl_xor(top[q], dd);
    merge_top8(top, o);
  }
  if (lg == 0) {
    int row = q0 + l15;
#pragma unroll
    for (int q = 0; q < 8; ++q) cand[((size_t)row * 8 + range) * 8 + q] = top[q];
  }
}

// ---------- merge + softmax + gate + gather + output: 4 rows per block ----------
__global__ __launch_bounds__(256) void k_final(const uint16_t* __restrict__ xb,
                                               const uint16_t* __restrict__ avb,
                                               const uint32_t* __restrict__ cand,
                                               const float* __restrict__ log_var,
                                               const float* __restrict__ uncp,
                                               const float* __restrict__ stats,
                                               const float* __restrict__ b2,
                                               const float* __restrict__ gw,
                                               const float* __restrict__ gb,
                                               float* __restrict__ out) {
  int tid = threadIdx.x;
  int wave = tid >> 6, lane = tid & 63;
  int row0 = blockIdx.x * 4;
  __shared__ float ws_[4][8]; __shared__ int wi_[4][8]; __shared__ float sg[4];
  {
    // each wave merges/gates its own row (wave-local, no barrier)
    int row = row0 + wave;
    uint32_t l[8];
    float up = 0.f;
    if (lane < 8) {
      const uint32_t* c = cand + (size_t)row * 64 + lane * 8;
#pragma unroll
      for (int q = 0; q < 8; ++q) l[q] = c[q];
      up = uncp[(size_t)row * 8 + lane];
    } else {
#pragma unroll
      for (int q = 0; q < 8; ++q) l[q] = 0u;
    }
#pragma unroll
    for (int d = 1; d < 8; d <<= 1) {
      uint32_t o[8];
#pragma unroll
      for (int q = 0; q < 8; ++q) o[q] = __shfl_xor(l[q], d);
      merge_top8(l, o);
      up += __shfl_xor(up, d);
    }
    if (lane == 0) {
      float sc[8];
#pragma unroll
      for (int q = 0; q < 8; ++q) sc[q] = unpack_score(l[q]);
      float mx = sc[7];
      float e[8]; float sum = 0.f;
#pragma unroll
      for (int q = 0; q < 8; ++q) { e[q] = expf(sc[q] - mx); sum += e[q]; }
      float inv = 1.f / sum;
#pragma unroll
      for (int q = 0; q < 8; ++q) { ws_[wave][q] = e[q] * inv; wi_[wave][q] = (int)(l[q] & 0xFFFu); }
      float learned = up + b2[0];
      float nv = log_var[row] * stats[0];
      float sig = 1.f / (1.f + expf(-learned));
      float u = nv * 0.5f + sig * 2.5f;
      u = fminf(fmaxf(u, 0.f), 5.f);
      sg[wave] = 1.f / (1.f + expf(-(gw[0] * u + gb[0])));
    }
  }
  __syncthreads();
  int h0 = tid * 4;
#pragma unroll
  for (int rr = 0; rr < 4; ++rr) {
    int row = row0 + rr;
    ushort4 hb = *reinterpret_cast<const ushort4*>(xb + (size_t)row * Hc + h0);
    float ax = 0.f, ay = 0.f, az = 0.f, aw = 0.f;
#pragma unroll
    for (int k = 0; k < 8; ++k) {
      float w = ws_[rr][k];
      ushort4 v = *reinterpret_cast<const ushort4*>(avb + (size_t)wi_[rr][k] * Hc + h0);
      ax = fmaf(w, bf2f(v.x), ax); ay = fmaf(w, bf2f(v.y), ay);
      az = fmaf(w, bf2f(v.z), az); aw = fmaf(w, bf2f(v.w), aw);
    }
    float g = sg[rr];
    float4 o;
    o.x = bf2f(hb.x) + g * ax; o.y = bf2f(hb.y) + g * ay;
    o.z = bf2f(hb.z) + g * az; o.w = bf2f(hb.w) + g * aw;
    *reinterpret_cast<float4*>(out + (size_t)row * Hc + h0) = o;
  }
}

extern "C" void kernel_launch(void* const* d_in, const int* in_sizes, int n_in,
                              void* d_out, int out_size, void* d_ws, size_t ws_size,
                              hipStream_t stream) {
  const float* hidden     = (const float*)d_in[0];
  const float* q_proj_w   = (const float*)d_in[1];
  const float* router_w   = (const float*)d_in[2];
  const float* aux_keys   = (const float*)d_in[3];
  const float* aux_values = (const float*)d_in[4];
  const float* rel        = (const float*)d_in[5];
  const float* unc_w1     = (const float*)d_in[6];
  const float* unc_b1     = (const float*)d_in[7];
  const float* unc_w2     = (const float*)d_in[8];
  const float* unc_b2     = (const float*)d_in[9];
  const float* gate_w1    = (const float*)d_in[10];
  const float* gate_bias  = (const float*)d_in[11];
  float* out = (float*)d_out;

  uint8_t* w = (uint8_t*)d_ws;              // ~28.5 MB used
  uint16_t* xb    = (uint16_t*)w;                 w += (size_t)ROWS * Hc * 2;     // 16 MB
  uint16_t* wcat  = (uint16_t*)w;                 w += (size_t)320 * Hc * 2;      // 640 KB
  uint16_t* avb   = (uint16_t*)w;                 w += (size_t)Nc * Hc * 2;       // 8 MB
  uint16_t* rq_b  = (uint16_t*)w;                 w += (size_t)ROWS * 64 * 2;     // 1 MB
  uint16_t* rk_b  = (uint16_t*)w;                 w += (size_t)Nc * 64 * 2;       // 512 KB
  float* log_var  = (float*)w;                    w += (size_t)ROWS * 4;
  float* uncp     = (float*)w;                    w += (size_t)ROWS * 8 * 4;      // 256 KB
  float* stats    = (float*)w;                    w += 256;
  uint32_t* cand  = (uint32_t*)w;                 w += (size_t)ROWS * 64 * 4;     // 2 MB

  k_prep_all<<<GP_W48 + GP_RK + GP_HB + GP_CVW + GP_CVA, NT, 0, stream>>>(
      hidden, q_proj_w, router_w, aux_keys, aux_values, rel, unc_w1,
      xb, log_var, wcat, avb, rk_b);
  k_xw<<<641, NT, 0, stream>>>(xb, wcat, unc_b1, unc_w2, log_var, stats, uncp, rq_b);
  k_scores_mfma<<<1024, NT, 0, stream>>>(rq_b, rk_b, cand);
  k_final<<<ROWS / 4, NT, 0, stream>>>(xb, avb, cand, log_var, uncp,
                                       stats, unc_b2, gate_w1, gate_bias, out);
}